// Round 1
// 352.418 us; speedup vs baseline: 1.0506x; 1.0506x over previous
//
#include <hip/hip_runtime.h>

// ---------------------------------------------------------------------------
// AttnBlock: GroupNorm -> q,k,v 1x1 conv -> softmax(QK^T/sqrt(c)) V -> out
// conv -> residual.  b=4, c=512, h=w=64 (n=4096), 32 groups.
// R8: gemm_qk_exp rewritten as 256x256-tile, 8-wave, BK=32 ring-4 LDS
//     pipeline with counted vmcnt(8) (never drained to 0 in steady state),
//     raw s_barrier phases and setprio around MFMA clusters (T3+T4+T5 on
//     top of the existing T2 swizzle).  Other GEMMs keep the R5/R7 128^2
//     double-buffered core.
// ---------------------------------------------------------------------------

typedef __attribute__((ext_vector_type(8))) short bf16x8;   // 8 bf16 (4 VGPR)
typedef __attribute__((ext_vector_type(4))) float f32x4;    // MFMA acc frag

#define MFMA16(a, b, c) __builtin_amdgcn_mfma_f32_16x16x32_bf16((a), (b), (c), 0, 0, 0)

#define B_   4
#define C_   512
#define N_   4096
#define SCALE 0.044194173824159216f  // 1/sqrt(512)
#define ESHIFT 12.0f                 // uniform exp shift (overflow insurance)

__device__ __forceinline__ unsigned short f2bf(float f) {
    union { float f; unsigned int u; } v; v.f = f;
    unsigned int r = (v.u + 0x7fffu + ((v.u >> 16) & 1u)) >> 16;  // RNE
    return (unsigned short)r;
}
__device__ __forceinline__ float bf2f(unsigned short s) {
    union { unsigned int u; float f; } v; v.u = ((unsigned int)s) << 16;
    return v.f;
}

// async 16B global -> LDS (lane i lands at lds + i*16)
__device__ __forceinline__ void async16(const unsigned short* g, unsigned short* l) {
    __builtin_amdgcn_global_load_lds((const __attribute__((address_space(1))) unsigned int*)g,
                                     (__attribute__((address_space(3))) unsigned int*)l,
                                     16, 0, 0);
}

// ---------------- GroupNorm partial sums: 512 blocks (4 per group) ----------
__global__ __launch_bounds__(256) void gn_partial(const float* __restrict__ x,
                                                  float* __restrict__ part) {
    int blk = blockIdx.x;           // 0..511
    int gid = blk >> 2, qtr = blk & 3;
    const float4* base = (const float4*)(x + (size_t)gid * 65536) + qtr * 4096;
    float s = 0.f, ss = 0.f;
    for (int i = threadIdx.x; i < 4096; i += 256) {
        float4 v = base[i];
        s  += v.x + v.y + v.z + v.w;
        ss += v.x * v.x + v.y * v.y + v.z * v.z + v.w * v.w;
    }
    __shared__ float red[512];
    int t = threadIdx.x;
    red[t] = s; red[256 + t] = ss;
    __syncthreads();
    for (int st = 128; st > 0; st >>= 1) {
        if (t < st) { red[t] += red[t + st]; red[256 + t] += red[256 + t + st]; }
        __syncthreads();
    }
    if (t == 0) { part[blk] = red[0]; part[512 + blk] = red[256]; }
}

// ------------- GroupNorm apply + transpose -> Ht[b][n][c] bf16 --------------
__global__ __launch_bounds__(256) void gn_apply(const float* __restrict__ x,
                                                const float* __restrict__ gamma,
                                                const float* __restrict__ beta,
                                                const float* __restrict__ part,
                                                unsigned short* __restrict__ ht) {
    __shared__ float tile[64][65];
    __shared__ float mrs[4][2];
    int j0 = blockIdx.x * 64, c0 = blockIdx.y * 64, b = blockIdx.z;
    int t = threadIdx.x;
    if (t < 4) {
        int gid = b * 32 + (c0 >> 4) + t;
        float s = 0.f, ss = 0.f;
#pragma unroll
        for (int q = 0; q < 4; ++q) { s += part[gid * 4 + q]; ss += part[512 + gid * 4 + q]; }
        float mean = s * (1.f / 65536.f);
        float var  = ss * (1.f / 65536.f) - mean * mean;
        mrs[t][0] = mean;
        mrs[t][1] = rsqrtf(var + 1e-6f);
    }
    __syncthreads();
#pragma unroll
    for (int i = 0; i < 16; ++i) {
        int lid = i * 256 + t;
        int cl = lid >> 6, jl = lid & 63;
        int c = c0 + cl;
        float v = x[((size_t)b * C_ + c) * N_ + j0 + jl];
        tile[cl][jl] = (v - mrs[cl >> 4][0]) * mrs[cl >> 4][1] * gamma[c] + beta[c];
    }
    __syncthreads();
#pragma unroll
    for (int i = 0; i < 16; ++i) {
        int lid = i * 256 + t;
        int jl = lid >> 6, cl = lid & 63;
        ht[((size_t)b * N_ + j0 + jl) * C_ + c0 + cl] = f2bf(tile[cl][jl]);
    }
}

// ------------- convert the 4 weight matrices to bf16 ------------------------
__global__ __launch_bounds__(256) void wconv(const float* __restrict__ wq,
                                             const float* __restrict__ wk,
                                             const float* __restrict__ wv,
                                             const float* __restrict__ wo,
                                             unsigned short* __restrict__ dst) {
    size_t i = (size_t)blockIdx.x * 256 + threadIdx.x;  // 4*512*512 total
    int m = (int)(i >> 18);
    size_t off = i & 262143;
    const float* src = (m == 0) ? wq : (m == 1) ? wk : (m == 2) ? wv : wo;
    dst[i] = f2bf(src[off]);
}

// ------------- 128x128xK MFMA GEMM core: dbuf + XOR-swizzled LDS ------------
// Staging (per tile): 16 segs x 8 rows x 128B; lane covers row (lane>>3),
// chunk (lane&7)^(lane>>3) -> slot s of row r holds chunk s^(r&7).
// Global: each 8-lane group reads one contiguous 128B row segment (coalesced).
// Fragment read: row*64 + ((kk*4+quad)^(l15&7))*8 -> every 8-lane group hits
// 8 distinct 4-bank groups: conflict-free.
// Pipeline: vmcnt(0); barrier; issue tile k+1 -> buf^1; compute buf[cur].
template <typename EPI>
__device__ __forceinline__ void gemm_core(const unsigned short* __restrict__ Abase,
                                          const unsigned short* __restrict__ Bbase,
                                          size_t lda, size_t ldb, int K, EPI epi) {
    __shared__ unsigned short hl[2][128 * 64];
    __shared__ unsigned short wl[2][128 * 64];
    int t = threadIdx.x;
    int wv = t >> 6, lane = t & 63, l15 = lane & 15, quad = lane >> 4;
    int wm = wv & 1, wn = wv >> 1;
    int srow = lane >> 3;                    // row within 8-row seg
    int sch  = ((lane & 7) ^ srow) * 8;      // XOR-swizzled chunk offset
    int xr = l15 & 7;
    f32x4 acc[4][4] = {};
    // prologue: stage tile 0 into buf 0
#pragma unroll
    for (int i = 0; i < 4; ++i) {
        int seg = wv * 4 + i;
        size_t row = seg * 8 + srow;
        async16(&Abase[row * lda + sch], &hl[0][seg * 512]);
        async16(&Bbase[row * ldb + sch], &wl[0][seg * 512]);
    }
    int nk = K >> 6;
    for (int k = 0; k < nk; ++k) {
        int cur = k & 1;
        __builtin_amdgcn_s_waitcnt(0x3F70);  // vmcnt(0): tile k staged (in flight
        __syncthreads();                     // through all of compute k-1)
        if (k + 1 < nk) {                    // prefetch k+1 (post-barrier: buf free)
            int k0 = (k + 1) << 6;
#pragma unroll
            for (int i = 0; i < 4; ++i) {
                int seg = wv * 4 + i;
                size_t row = seg * 8 + srow;
                async16(&Abase[row * lda + k0 + sch], &hl[cur ^ 1][seg * 512]);
                async16(&Bbase[row * ldb + k0 + sch], &wl[cur ^ 1][seg * 512]);
            }
        }
#pragma unroll
        for (int kk = 0; kk < 2; ++kk) {
            int sl = (((kk << 2) + quad) ^ xr) * 8;
            bf16x8 af[4], bfr[4];
#pragma unroll
            for (int mi = 0; mi < 4; ++mi)
                af[mi] = *(const bf16x8*)&hl[cur][(wm * 64 + mi * 16 + l15) * 64 + sl];
#pragma unroll
            for (int ni = 0; ni < 4; ++ni)
                bfr[ni] = *(const bf16x8*)&wl[cur][(wn * 64 + ni * 16 + l15) * 64 + sl];
#pragma unroll
            for (int mi = 0; mi < 4; ++mi)
#pragma unroll
                for (int ni = 0; ni < 4; ++ni)
                    acc[mi][ni] = MFMA16(af[mi], bfr[ni], acc[mi][ni]);
        }
    }
    epi(acc, wm, wn, l15, quad);
}

// ------------- fused QKV projection: grid (32, 12, 4) -----------------------
__global__ __launch_bounds__(256) void gemm_qkv(const unsigned short* __restrict__ Ht,
                                                const unsigned short* __restrict__ Wb,
                                                const float* __restrict__ bq,
                                                const float* __restrict__ bk,
                                                const float* __restrict__ bv,
                                                unsigned short* __restrict__ Qt,
                                                unsigned short* __restrict__ Kt,
                                                unsigned short* __restrict__ Vg) {
    int b = blockIdx.z, j0 = blockIdx.x * 128;
    int ct = blockIdx.y;                 // 0..11
    int slab = ct >> 2, co0 = (ct & 3) * 128;
    const unsigned short* A = Ht + ((size_t)b * N_ + j0) * C_;
    const unsigned short* B = Wb + (size_t)slab * C_ * C_ + (size_t)co0 * C_;
    const float* bias = (slab == 0) ? bq : (slab == 1) ? bk : bv;
    unsigned short* outqk = (slab == 0) ? Qt : Kt;
    gemm_core(A, B, C_, C_, C_,
        [&](f32x4 (&acc)[4][4], int wm, int wn, int l15, int quad) {
        if (slab < 2) {
#pragma unroll
            for (int mi = 0; mi < 4; ++mi)
#pragma unroll
                for (int ni = 0; ni < 4; ++ni)
#pragma unroll
                    for (int r = 0; r < 4; ++r) {
                        int mrow = wm * 64 + mi * 16 + quad * 4 + r;
                        int ncol = wn * 64 + ni * 16 + l15;
                        outqk[((size_t)b * N_ + j0 + mrow) * C_ + co0 + ncol] =
                            f2bf(acc[mi][ni][r] + bias[co0 + ncol]);
                    }
        } else {
#pragma unroll
            for (int mi = 0; mi < 4; ++mi)
#pragma unroll
                for (int ni = 0; ni < 4; ++ni) {
                    int ncol = wn * 64 + ni * 16 + l15;
                    float bb = bias[co0 + ncol];
                    ushort4 pk;
                    pk.x = f2bf(acc[mi][ni][0] + bb);
                    pk.y = f2bf(acc[mi][ni][1] + bb);
                    pk.z = f2bf(acc[mi][ni][2] + bb);
                    pk.w = f2bf(acc[mi][ni][3] + bb);
                    int jb = j0 + wm * 64 + mi * 16 + quad * 4;
                    *(ushort4*)&Vg[((size_t)b * C_ + co0 + ncol) * N_ + jb] = pk;
                }
        }
    });
}

// ------------- GEMM1 (R8): P = exp(Q K^T * scale - 12), rowsum partials -----
// 256x256 tile, 8 waves (2M x 4N, per-wave 128x64), BK=32, ring of 4 LDS
// K-tile buffers (4 x 32 KiB = 128 KiB dynamic LDS).  Staging runs 3 K-tiles
// ahead; tile-boundary waits are counted vmcnt(8) (2 tiles stay in flight),
// draining only for the last two tiles.  Raw s_barrier phases (no vmcnt(0)
// drain), s_setprio(1) around each 16-MFMA cluster.
// LDS row = 32 bf16 = 64B = 4 chunks of 16B; slot s of row r holds chunk
// s ^ ((r>>1)&3)  -> frag ds_read_b128 lands 2 lanes/bank (free).
// psum layout: [wn*16 + ktile][b*4096+q] f32 (64 x 16384) - same 64 slabs as
// before, so gemm_pv's reduction is unchanged.
__global__ __launch_bounds__(512, 2) void gemm_qk_exp(const unsigned short* __restrict__ Qt,
                                                      const unsigned short* __restrict__ Kt,
                                                      unsigned short* __restrict__ P,
                                                      float* __restrict__ psum) {
    extern __shared__ unsigned short sm[];   // 4 bufs x (A 8192 | B 8192) ushorts
    int b = blockIdx.z, j0 = blockIdx.x * 256, ky = blockIdx.y;
    int kc0 = ky * 256;
    const unsigned short* A  = Qt + ((size_t)b * N_ + j0) * C_;
    const unsigned short* Bm = Kt + ((size_t)b * N_ + kc0) * C_;

    int t = threadIdx.x;
    int w = t >> 6, lane = t & 63, l15 = lane & 15, quad = lane >> 4;
    int wm = w >> 2, wn = w & 3;
    int srow = lane >> 2;                              // row within 16-row seg
    int sch  = (((lane & 3) ^ ((lane >> 3) & 3))) * 8; // swizzled source chunk (elems)
    int slotq = (quad ^ ((l15 >> 1) & 3)) * 8;         // frag-read slot (elems)

    f32x4 acc[8][4] = {};

    const int NT = 16;                       // K=512 / BK=32
    // prologue: stage tiles 0..2 into bufs 0..2 (12 loads/thread)
#pragma unroll
    for (int tt = 0; tt < 3; ++tt) {
        unsigned short* dst = sm + (tt << 14);
        size_t k0 = (size_t)tt << 5;
#pragma unroll
        for (int i = 0; i < 2; ++i) {
            int seg = w * 2 + i;
            size_t row = (size_t)seg * 16 + srow;
            async16(&A [row * C_ + k0 + sch], dst + seg * 512);
            async16(&Bm[row * C_ + k0 + sch], dst + 8192 + seg * 512);
        }
    }
    __builtin_amdgcn_s_waitcnt(0x3F78);      // vmcnt(8): tile 0 landed
    __builtin_amdgcn_s_barrier();

    for (int tt = 0; tt < NT; ++tt) {
        const unsigned short* bp = sm + ((tt & 3) << 14);
        unsigned short* stg = sm + (((tt + 3) & 3) << 14);
        const bool dostage = (tt + 3 < NT);
        size_t k0n = (size_t)(tt + 3) << 5;
        // ---- phase A: read B-frags + A-frags mi0..3, stage A half of t+3
        bf16x8 bfr[4], af[4];
#pragma unroll
        for (int ni = 0; ni < 4; ++ni)
            bfr[ni] = *(const bf16x8*)&bp[8192 + (wn * 64 + ni * 16 + l15) * 32 + slotq];
#pragma unroll
        for (int mi = 0; mi < 4; ++mi)
            af[mi] = *(const bf16x8*)&bp[(wm * 128 + mi * 16 + l15) * 32 + slotq];
        if (dostage) {
#pragma unroll
            for (int i = 0; i < 2; ++i) {
                int seg = w * 2 + i;
                size_t row = (size_t)seg * 16 + srow;
                async16(&A[row * C_ + k0n + sch], stg + seg * 512);
            }
        }
        __builtin_amdgcn_s_barrier();
        __builtin_amdgcn_s_setprio(1);
#pragma unroll
        for (int mi = 0; mi < 4; ++mi)
#pragma unroll
            for (int ni = 0; ni < 4; ++ni)
                acc[mi][ni] = MFMA16(af[mi], bfr[ni], acc[mi][ni]);
        __builtin_amdgcn_s_setprio(0);
        __builtin_amdgcn_s_barrier();
        // ---- phase B: read A-frags mi4..7, stage B half of t+3
#pragma unroll
        for (int mi = 0; mi < 4; ++mi)
            af[mi] = *(const bf16x8*)&bp[(wm * 128 + (mi + 4) * 16 + l15) * 32 + slotq];
        if (dostage) {
#pragma unroll
            for (int i = 0; i < 2; ++i) {
                int seg = w * 2 + i;
                size_t row = (size_t)seg * 16 + srow;
                async16(&Bm[row * C_ + k0n + sch], stg + 8192 + seg * 512);
            }
        }
        __builtin_amdgcn_s_barrier();
        __builtin_amdgcn_s_setprio(1);
#pragma unroll
        for (int mi = 0; mi < 4; ++mi)
#pragma unroll
            for (int ni = 0; ni < 4; ++ni)
                acc[4 + mi][ni] = MFMA16(af[mi], bfr[ni], acc[4 + mi][ni]);
        __builtin_amdgcn_s_setprio(0);
        // ---- tile boundary: counted wait for tile tt+1's staging
        if (tt + 1 < NT) {
            if (tt < NT - 3)       __builtin_amdgcn_s_waitcnt(0x3F78); // vmcnt(8)
            else if (tt == NT - 3) __builtin_amdgcn_s_waitcnt(0x3F74); // vmcnt(4)
            else                   __builtin_amdgcn_s_waitcnt(0x3F70); // vmcnt(0)
            __builtin_amdgcn_s_barrier();
        }
    }

    // ---- epilogue: exp + P store + per-wave rowsum partials
#pragma unroll
    for (int mi = 0; mi < 8; ++mi) {
        float rs[4] = {0.f, 0.f, 0.f, 0.f};
#pragma unroll
        for (int ni = 0; ni < 4; ++ni) {
            int ncol = kc0 + wn * 64 + ni * 16 + l15;
#pragma unroll
            for (int r = 0; r < 4; ++r) {
                int mrow = j0 + wm * 128 + mi * 16 + quad * 4 + r;
                float p = __expf(acc[mi][ni][r] * SCALE - ESHIFT);
                rs[r] += p;
                P[((size_t)b * N_ + mrow) * N_ + ncol] = f2bf(p);
            }
        }
#pragma unroll
        for (int r = 0; r < 4; ++r) {
            float v = rs[r];
            v += __shfl_xor(v, 1);
            v += __shfl_xor(v, 2);
            v += __shfl_xor(v, 4);
            v += __shfl_xor(v, 8);
            if (l15 == 0)
                psum[(size_t)(wn * 16 + ky) * 16384 +
                     (size_t)b * N_ + j0 + wm * 128 + mi * 16 + quad * 4 + r] = v;
        }
    }
}

// ------------- GEMM2: O = (P V) / l -> AObf[b][n][c] bf16 -------------------
__global__ __launch_bounds__(256) void gemm_pv(const unsigned short* __restrict__ P,
                                               const unsigned short* __restrict__ Vg,
                                               const float* __restrict__ psum,
                                               unsigned short* __restrict__ ao) {
    __shared__ float linv[128];
    int flat = blockIdx.x;
    int xcd = flat & 7, rr = flat >> 3;
    int ct = rr & 3, g = (rr >> 2) * 8 + xcd;   // g in [0,128)
    int b = g & 3, qtile = g >> 2;
    int j0 = qtile * 128, co0 = ct * 128;
    int t = threadIdx.x;
    if (t < 128) {
        size_t q = (size_t)b * N_ + j0 + t;
        float s = 0.f;
#pragma unroll
        for (int i = 0; i < 64; ++i) s += psum[(size_t)i * 16384 + q];
        linv[t] = 1.f / s;
    }
    const unsigned short* A = P + ((size_t)b * N_ + j0) * N_;
    const unsigned short* B = Vg + ((size_t)b * C_ + co0) * N_;
    gemm_core(A, B, N_, N_, N_,
        [&](f32x4 (&acc)[4][4], int wm, int wn, int l15, int quad) {
#pragma unroll
        for (int mi = 0; mi < 4; ++mi)
#pragma unroll
            for (int ni = 0; ni < 4; ++ni)
#pragma unroll
                for (int r = 0; r < 4; ++r) {
                    int mrow = wm * 64 + mi * 16 + quad * 4 + r;
                    int ncol = wn * 64 + ni * 16 + l15;
                    ao[((size_t)b * N_ + j0 + mrow) * C_ + co0 + ncol] =
                        f2bf(acc[mi][ni][r] * linv[mrow]);
                }
    });
}

// ------------- final projection + residual: grid (32, 4, 4) -----------------
__global__ __launch_bounds__(256) void gemm_resid(const unsigned short* __restrict__ AObf,
                                                  const unsigned short* __restrict__ Wo,
                                                  const float* __restrict__ bo,
                                                  const float* __restrict__ xres,
                                                  float* __restrict__ out) {
    int b = blockIdx.z, j0 = blockIdx.x * 128, co0 = blockIdx.y * 128;
    const unsigned short* A = AObf + ((size_t)b * N_ + j0) * C_;
    const unsigned short* B = Wo + (size_t)co0 * C_;
    gemm_core(A, B, C_, C_, C_,
        [&](f32x4 (&acc)[4][4], int wm, int wn, int l15, int quad) {
#pragma unroll
        for (int mi = 0; mi < 4; ++mi)
#pragma unroll
            for (int ni = 0; ni < 4; ++ni) {
                int ncol = wn * 64 + ni * 16 + l15;
                int jb = j0 + wm * 64 + mi * 16 + quad * 4;
                size_t o = ((size_t)b * C_ + co0 + ncol) * N_ + jb;
                float bb = bo[co0 + ncol];
                float4 xr = *(const float4*)&xres[o];
                float4 ov;
                ov.x = acc[mi][ni][0] + bb + xr.x;
                ov.y = acc[mi][ni][1] + bb + xr.y;
                ov.z = acc[mi][ni][2] + bb + xr.z;
                ov.w = acc[mi][ni][3] + bb + xr.w;
                *(float4*)&out[o] = ov;
            }
    });
}

// ------------- FALLBACK: R4 flash attention (if ws too small) ---------------
__global__ __launch_bounds__(256, 1) void flash_attn(const unsigned short* __restrict__ Qt,
                                                     const unsigned short* __restrict__ Kt,
                                                     const unsigned short* __restrict__ Vg,
                                                     unsigned short* __restrict__ part,
                                                     float* __restrict__ lbuf,
                                                     int nsplit) {
    extern __shared__ unsigned short smem[];
    unsigned short* Kl = smem;
    unsigned short* Vl = smem + 32768;
    unsigned short* Pl = smem + 65536;

    int flat = blockIdx.x;
    int qblk, b, s;
    if (nsplit == 2) { s = flat & 1; b = (flat >> 1) & 3; qblk = flat >> 3; }
    else             { s = 0;        b = flat & 3;        qblk = flat >> 2; }
    int q0 = qblk * 128;
    int t = threadIdx.x, w = t >> 6, lane = t & 63, l15 = lane & 15, quad = lane >> 4;
    int klen = N_ / nsplit, kbeg = s * klen, nkt = klen / 32;
    int xr = l15 & 7;

    const unsigned short* Kbase = Kt + (size_t)b * N_ * C_;
    const unsigned short* Vbase = Vg + (size_t)b * C_ * N_;

    bf16x8 qa[2][16];
#pragma unroll
    for (int u = 0; u < 2; ++u) {
        const unsigned short* qb =
            Qt + ((size_t)b * N_ + q0 + w * 32 + u * 16 + l15) * C_ + quad * 8;
#pragma unroll
        for (int ck = 0; ck < 16; ++ck) qa[u][ck] = *(const bf16x8*)(qb + ck * 32);
    }

    f32x4 o[2][32] = {};
    float lrow[2][4] = {};

    {
        int k0 = kbeg;
#pragma unroll
        for (int i = 0; i < 8; ++i) {
            int r = w * 8 + i;
            async16(Kbase + (size_t)(k0 + r) * C_ + ((lane ^ (r & 7)) * 8), Kl + r * 512);
        }
#pragma unroll
        for (int i = 0; i < 8; ++i) {
            int idx = w * 8 + i, kc = idx >> 3, cb = idx & 7;
            async16(Vbase + (size_t)(cb * 64 + lane) * N_ + k0 + kc * 8,
                    Vl + (kc * 512 + cb * 64) * 8);
        }
    }

    for (int kt = 0; kt < nkt; ++kt) {
        int cur = kt & 1, nxt = cur ^ 1;
        __builtin_amdgcn_s_waitcnt(0x3F70);
        __syncthreads();
        if (kt + 1 < nkt) {
            int k0 = kbeg + (kt + 1) * 32;
#pragma unroll
            for (int i = 0; i < 8; ++i) {
                int r = w * 8 + i;
                async16(Kbase + (size_t)(k0 + r) * C_ + ((lane ^ (r & 7)) * 8),
                        Kl + nxt * 16384 + r * 512);
            }
#pragma unroll
            for (int i = 0; i < 8; ++i) {
                int idx = w * 8 + i, kc = idx >> 3, cb = idx & 7;
                async16(Vbase + (size_t)(cb * 64 + lane) * N_ + k0 + kc * 8,
                        Vl + nxt * 16384 + (kc * 512 + cb * 64) * 8);
            }
        }
        const unsigned short* Kc = Kl + cur * 16384;
        f32x4 s00 = {}, s01 = {}, s10 = {}, s11 = {};
#pragma unroll
        for (int ck = 0; ck < 16; ++ck) {
            int slot = (ck * 4 + quad) ^ xr;
            bf16x8 b0 = *(const bf16x8*)&Kc[l15 * 512 + slot * 8];
            bf16x8 b1 = *(const bf16x8*)&Kc[(16 + l15) * 512 + slot * 8];
            s00 = MFMA16(qa[0][ck], b0, s00);
            s10 = MFMA16(qa[1][ck], b0, s10);
            s01 = MFMA16(qa[0][ck], b1, s01);
            s11 = MFMA16(qa[1][ck], b1, s11);
        }
        unsigned short* pb = &Pl[w * 1152];
#pragma unroll
        for (int r = 0; r < 4; ++r) {
            float p00 = __expf(s00[r] * SCALE - ESHIFT);
            float p01 = __expf(s01[r] * SCALE - ESHIFT);
            float p10 = __expf(s10[r] * SCALE - ESHIFT);
            float p11 = __expf(s11[r] * SCALE - ESHIFT);
            lrow[0][r] += p00 + p01;
            lrow[1][r] += p10 + p11;
            int row0 = (quad * 4 + r) * 36;
            int row1 = (16 + quad * 4 + r) * 36;
            pb[row0 + l15]      = f2bf(p00);
            pb[row0 + 16 + l15] = f2bf(p01);
            pb[row1 + l15]      = f2bf(p10);
            pb[row1 + 16 + l15] = f2bf(p11);
        }
        __builtin_amdgcn_s_waitcnt(0xC07F);
        bf16x8 pa0 = *(const bf16x8*)&Pl[w * 1152 + l15 * 36 + quad * 8];
        bf16x8 pa1 = *(const bf16x8*)&Pl[w * 1152 + (16 + l15) * 36 + quad * 8];
        const unsigned short* Vc = Vl + cur * 16384;
#pragma unroll
        for (int cf = 0; cf < 32; ++cf) {
            bf16x8 vb = *(const bf16x8*)&Vc[(quad * 512 + cf * 16 + l15) * 8];
            o[0][cf] = MFMA16(pa0, vb, o[0][cf]);
            o[1][cf] = MFMA16(pa1, vb, o[1][cf]);
        }
    }
#pragma unroll
    for (int u = 0; u < 2; ++u)
#pragma unroll
        for (int r = 0; r < 4; ++r) {
            float l = lrow[u][r];
            l += __shfl_xor(l, 1);
            l += __shfl_xor(l, 2);
            l += __shfl_xor(l, 4);
            l += __shfl_xor(l, 8);
            lrow[u][r] = l;
        }
    size_t pbase = (size_t)(s * B_ + b) * N_;
#pragma unroll
    for (int u = 0; u < 2; ++u)
#pragma unroll
        for (int cf = 0; cf < 32; ++cf)
#pragma unroll
            for (int r = 0; r < 4; ++r) {
                int q = q0 + w * 32 + u * 16 + quad * 4 + r;
                part[(pbase + q) * C_ + cf * 16 + l15] = f2bf(o[u][cf][r]);
            }
    if (l15 == 0) {
#pragma unroll
        for (int u = 0; u < 2; ++u)
#pragma unroll
            for (int r = 0; r < 4; ++r) {
                int q = q0 + w * 32 + u * 16 + quad * 4 + r;
                lbuf[pbase + q] = lrow[u][r];
            }
    }
}

__global__ __launch_bounds__(256) void attn_combine(const unsigned short* __restrict__ part,
                                                    const float* __restrict__ lbuf,
                                                    unsigned short* __restrict__ ao,
                                                    int nsplit) {
    size_t idx = (size_t)blockIdx.x * 256 + threadIdx.x;
    int cu = (int)(idx & 63);
    size_t row = idx >> 6;
    float l = lbuf[row];
    union { uint4 v; unsigned short u[8]; } p1, p2, outv;
    p1.v = *(const uint4*)&part[row * C_ + cu * 8];
    if (nsplit == 2) {
        l += lbuf[(size_t)B_ * N_ + row];
        p2.v = *(const uint4*)&part[((size_t)B_ * N_ + row) * C_ + cu * 8];
    } else {
        p2.v = make_uint4(0, 0, 0, 0);
    }
    float inv = 1.f / l;
#pragma unroll
    for (int j = 0; j < 8; ++j)
        outv.u[j] = f2bf((bf2f(p1.u[j]) + bf2f(p2.u[j])) * inv);
    *(uint4*)&ao[row * C_ + cu * 8] = outv.v;
}

// ---------------------------------------------------------------------------
extern "C" void kernel_launch(void* const* d_in, const int* in_sizes, int n_in,
                              void* d_out, int out_size, void* d_ws, size_t ws_size,
                              hipStream_t stream) {
    const float* x   = (const float*)d_in[0];
    const float* gam = (const float*)d_in[1];
    const float* bet = (const float*)d_in[2];
    const float* wq  = (const float*)d_in[3];
    const float* bq  = (const float*)d_in[4];
    const float* wk  = (const float*)d_in[5];
    const float* bk  = (const float*)d_in[6];
    const float* wv  = (const float*)d_in[7];
    const float* bv  = (const float*)d_in[8];
    const float* wo  = (const float*)d_in[9];
    const float* bo  = (const float*)d_in[10];
    float* out = (float*)d_out;

    char* ws = (char*)d_ws;
    const size_t SZH = (size_t)B_ * N_ * C_ * 2;          // 16 MiB bf16 tensor
    const size_t OFF_HT = 4096;
    const size_t OFF_QT = OFF_HT + SZH;
    const size_t OFF_KT = OFF_QT + SZH;
    const size_t OFF_VG = OFF_KT + SZH;
    const size_t OFF_WB = OFF_VG + SZH;
    const size_t OFF_X  = OFF_WB + 2097152;               // 69,210,112
    float*          part0 = (float*)ws;                   // gn partial sums
    unsigned short* Ht    = (unsigned short*)(ws + OFF_HT);
    unsigned short* Qt    = (unsigned short*)(ws + OFF_QT);
    unsigned short* Kt    = (unsigned short*)(ws + OFF_KT);
    unsigned short* Vg    = (unsigned short*)(ws + OFF_VG);
    unsigned short* Wb    = (unsigned short*)(ws + OFF_WB);
    unsigned short* AObf  = Ht;  // Ht dead after projections

    // Path A: materialized-P two-GEMM attention.
    const size_t SZPSUM = 64ull * 16384 * 4;              // 4 MiB
    const size_t SZP    = (size_t)B_ * N_ * N_ * 2;       // 128 MiB
    float*          psum = (float*)(ws + OFF_X);
    unsigned short* P    = (unsigned short*)(ws + OFF_X + SZPSUM);
    size_t needA = OFF_X + SZPSUM + SZP;

    // Path B (fallback): R4 flash.
    float*          lbuf = (float*)(ws + OFF_X);
    unsigned short* partb = (unsigned short*)(ws + OFF_X + 262144);
    size_t needB2 = OFF_X + 262144 + 2 * SZH;

    gn_partial<<<512, 256, 0, stream>>>(x, part0);
    gn_apply<<<dim3(64, 8, B_), 256, 0, stream>>>(x, gam, bet, part0, Ht);
    wconv<<<4096, 256, 0, stream>>>(wq, wk, wv, wo, Wb);
    gemm_qkv<<<dim3(32, 12, B_), 256, 0, stream>>>(Ht, Wb, bq, bk, bv, Qt, Kt, Vg);

    if (ws_size >= needA) {
        const int QK_LDS = 131072;   // 4 ring bufs x 32 KiB
        (void)hipFuncSetAttribute((const void*)gemm_qk_exp,
                                  hipFuncAttributeMaxDynamicSharedMemorySize, QK_LDS);
        gemm_qk_exp<<<dim3(16, 16, B_), 512, QK_LDS, stream>>>(Qt, Kt, P, psum);
        gemm_pv<<<512, 256, 0, stream>>>(P, Vg, psum, AObf);
    } else {
        int nsplit = (ws_size >= needB2) ? 2 : 1;
        const int FLASH_LDS = 140288;
        (void)hipFuncSetAttribute((const void*)flash_attn,
                                  hipFuncAttributeMaxDynamicSharedMemorySize, FLASH_LDS);
        flash_attn<<<dim3(32 * B_ * nsplit), 256, FLASH_LDS, stream>>>(Qt, Kt, Vg, partb, lbuf, nsplit);
        attn_combine<<<4096, 256, 0, stream>>>(partb, lbuf, AObf, nsplit);
    }
    gemm_resid<<<dim3(32, 4, B_), 256, 0, stream>>>(AObf, Wb + 786432, bo, x, out);
}

// Round 2
// 341.807 us; speedup vs baseline: 1.0832x; 1.0310x over previous
//
#include <hip/hip_runtime.h>

// ---------------------------------------------------------------------------
// AttnBlock: GroupNorm -> q,k,v 1x1 conv -> softmax(QK^T/sqrt(c)) V -> out
// conv -> residual.  b=4, c=512, h=w=64 (n=4096), 32 groups.
// R9: gemm_pv rewritten as 256x128-tile, 8-wave, BK=32 ring-4 deep pipeline
//     (counted vmcnt(6), 2 barriers/tile, K=4096 so no tail); XCD rectangle
//     swizzle on both attention GEMMs so staged panels are L2-resident
//     (qk: 4x8 Q/K rect = 3 MB < 4 MB L2/XCD; pv: 4 ct-blocks sharing a
//     P-tile co-located per XCD).  qk loop structure unchanged from R8
//     (register-capped at 1 block/CU: acc[8][4]=128 AGPR + 108 VGPR).
// ---------------------------------------------------------------------------

typedef __attribute__((ext_vector_type(8))) short bf16x8;   // 8 bf16 (4 VGPR)
typedef __attribute__((ext_vector_type(4))) float f32x4;    // MFMA acc frag

#define MFMA16(a, b, c) __builtin_amdgcn_mfma_f32_16x16x32_bf16((a), (b), (c), 0, 0, 0)

#define B_   4
#define C_   512
#define N_   4096
#define SCALE 0.044194173824159216f  // 1/sqrt(512)
#define ESHIFT 12.0f                 // uniform exp shift (overflow insurance)

__device__ __forceinline__ unsigned short f2bf(float f) {
    union { float f; unsigned int u; } v; v.f = f;
    unsigned int r = (v.u + 0x7fffu + ((v.u >> 16) & 1u)) >> 16;  // RNE
    return (unsigned short)r;
}
__device__ __forceinline__ float bf2f(unsigned short s) {
    union { unsigned int u; float f; } v; v.u = ((unsigned int)s) << 16;
    return v.f;
}

// async 16B global -> LDS (lane i lands at lds + i*16)
__device__ __forceinline__ void async16(const unsigned short* g, unsigned short* l) {
    __builtin_amdgcn_global_load_lds((const __attribute__((address_space(1))) unsigned int*)g,
                                     (__attribute__((address_space(3))) unsigned int*)l,
                                     16, 0, 0);
}

// ---------------- GroupNorm partial sums: 512 blocks (4 per group) ----------
__global__ __launch_bounds__(256) void gn_partial(const float* __restrict__ x,
                                                  float* __restrict__ part) {
    int blk = blockIdx.x;           // 0..511
    int gid = blk >> 2, qtr = blk & 3;
    const float4* base = (const float4*)(x + (size_t)gid * 65536) + qtr * 4096;
    float s = 0.f, ss = 0.f;
    for (int i = threadIdx.x; i < 4096; i += 256) {
        float4 v = base[i];
        s  += v.x + v.y + v.z + v.w;
        ss += v.x * v.x + v.y * v.y + v.z * v.z + v.w * v.w;
    }
    __shared__ float red[512];
    int t = threadIdx.x;
    red[t] = s; red[256 + t] = ss;
    __syncthreads();
    for (int st = 128; st > 0; st >>= 1) {
        if (t < st) { red[t] += red[t + st]; red[256 + t] += red[256 + t + st]; }
        __syncthreads();
    }
    if (t == 0) { part[blk] = red[0]; part[512 + blk] = red[256]; }
}

// ------------- GroupNorm apply + transpose -> Ht[b][n][c] bf16 --------------
__global__ __launch_bounds__(256) void gn_apply(const float* __restrict__ x,
                                                const float* __restrict__ gamma,
                                                const float* __restrict__ beta,
                                                const float* __restrict__ part,
                                                unsigned short* __restrict__ ht) {
    __shared__ float tile[64][65];
    __shared__ float mrs[4][2];
    int j0 = blockIdx.x * 64, c0 = blockIdx.y * 64, b = blockIdx.z;
    int t = threadIdx.x;
    if (t < 4) {
        int gid = b * 32 + (c0 >> 4) + t;
        float s = 0.f, ss = 0.f;
#pragma unroll
        for (int q = 0; q < 4; ++q) { s += part[gid * 4 + q]; ss += part[512 + gid * 4 + q]; }
        float mean = s * (1.f / 65536.f);
        float var  = ss * (1.f / 65536.f) - mean * mean;
        mrs[t][0] = mean;
        mrs[t][1] = rsqrtf(var + 1e-6f);
    }
    __syncthreads();
#pragma unroll
    for (int i = 0; i < 16; ++i) {
        int lid = i * 256 + t;
        int cl = lid >> 6, jl = lid & 63;
        int c = c0 + cl;
        float v = x[((size_t)b * C_ + c) * N_ + j0 + jl];
        tile[cl][jl] = (v - mrs[cl >> 4][0]) * mrs[cl >> 4][1] * gamma[c] + beta[c];
    }
    __syncthreads();
#pragma unroll
    for (int i = 0; i < 16; ++i) {
        int lid = i * 256 + t;
        int jl = lid >> 6, cl = lid & 63;
        ht[((size_t)b * N_ + j0 + jl) * C_ + c0 + cl] = f2bf(tile[cl][jl]);
    }
}

// ------------- convert the 4 weight matrices to bf16 ------------------------
__global__ __launch_bounds__(256) void wconv(const float* __restrict__ wq,
                                             const float* __restrict__ wk,
                                             const float* __restrict__ wv,
                                             const float* __restrict__ wo,
                                             unsigned short* __restrict__ dst) {
    size_t i = (size_t)blockIdx.x * 256 + threadIdx.x;  // 4*512*512 total
    int m = (int)(i >> 18);
    size_t off = i & 262143;
    const float* src = (m == 0) ? wq : (m == 1) ? wk : (m == 2) ? wv : wo;
    dst[i] = f2bf(src[off]);
}

// ------------- 128x128xK MFMA GEMM core: dbuf + XOR-swizzled LDS ------------
template <typename EPI>
__device__ __forceinline__ void gemm_core(const unsigned short* __restrict__ Abase,
                                          const unsigned short* __restrict__ Bbase,
                                          size_t lda, size_t ldb, int K, EPI epi) {
    __shared__ unsigned short hl[2][128 * 64];
    __shared__ unsigned short wl[2][128 * 64];
    int t = threadIdx.x;
    int wv = t >> 6, lane = t & 63, l15 = lane & 15, quad = lane >> 4;
    int wm = wv & 1, wn = wv >> 1;
    int srow = lane >> 3;                    // row within 8-row seg
    int sch  = ((lane & 7) ^ srow) * 8;      // XOR-swizzled chunk offset
    int xr = l15 & 7;
    f32x4 acc[4][4] = {};
    // prologue: stage tile 0 into buf 0
#pragma unroll
    for (int i = 0; i < 4; ++i) {
        int seg = wv * 4 + i;
        size_t row = seg * 8 + srow;
        async16(&Abase[row * lda + sch], &hl[0][seg * 512]);
        async16(&Bbase[row * ldb + sch], &wl[0][seg * 512]);
    }
    int nk = K >> 6;
    for (int k = 0; k < nk; ++k) {
        int cur = k & 1;
        __builtin_amdgcn_s_waitcnt(0x3F70);  // vmcnt(0)
        __syncthreads();
        if (k + 1 < nk) {                    // prefetch k+1 (post-barrier: buf free)
            int k0 = (k + 1) << 6;
#pragma unroll
            for (int i = 0; i < 4; ++i) {
                int seg = wv * 4 + i;
                size_t row = seg * 8 + srow;
                async16(&Abase[row * lda + k0 + sch], &hl[cur ^ 1][seg * 512]);
                async16(&Bbase[row * ldb + k0 + sch], &wl[cur ^ 1][seg * 512]);
            }
        }
#pragma unroll
        for (int kk = 0; kk < 2; ++kk) {
            int sl = (((kk << 2) + quad) ^ xr) * 8;
            bf16x8 af[4], bfr[4];
#pragma unroll
            for (int mi = 0; mi < 4; ++mi)
                af[mi] = *(const bf16x8*)&hl[cur][(wm * 64 + mi * 16 + l15) * 64 + sl];
#pragma unroll
            for (int ni = 0; ni < 4; ++ni)
                bfr[ni] = *(const bf16x8*)&wl[cur][(wn * 64 + ni * 16 + l15) * 64 + sl];
#pragma unroll
            for (int mi = 0; mi < 4; ++mi)
#pragma unroll
                for (int ni = 0; ni < 4; ++ni)
                    acc[mi][ni] = MFMA16(af[mi], bfr[ni], acc[mi][ni]);
        }
    }
    epi(acc, wm, wn, l15, quad);
}

// ------------- fused QKV projection: grid (32, 12, 4) -----------------------
__global__ __launch_bounds__(256) void gemm_qkv(const unsigned short* __restrict__ Ht,
                                                const unsigned short* __restrict__ Wb,
                                                const float* __restrict__ bq,
                                                const float* __restrict__ bk,
                                                const float* __restrict__ bv,
                                                unsigned short* __restrict__ Qt,
                                                unsigned short* __restrict__ Kt,
                                                unsigned short* __restrict__ Vg) {
    int b = blockIdx.z, j0 = blockIdx.x * 128;
    int ct = blockIdx.y;                 // 0..11
    int slab = ct >> 2, co0 = (ct & 3) * 128;
    const unsigned short* A = Ht + ((size_t)b * N_ + j0) * C_;
    const unsigned short* B = Wb + (size_t)slab * C_ * C_ + (size_t)co0 * C_;
    const float* bias = (slab == 0) ? bq : (slab == 1) ? bk : bv;
    unsigned short* outqk = (slab == 0) ? Qt : Kt;
    gemm_core(A, B, C_, C_, C_,
        [&](f32x4 (&acc)[4][4], int wm, int wn, int l15, int quad) {
        if (slab < 2) {
#pragma unroll
            for (int mi = 0; mi < 4; ++mi)
#pragma unroll
                for (int ni = 0; ni < 4; ++ni)
#pragma unroll
                    for (int r = 0; r < 4; ++r) {
                        int mrow = wm * 64 + mi * 16 + quad * 4 + r;
                        int ncol = wn * 64 + ni * 16 + l15;
                        outqk[((size_t)b * N_ + j0 + mrow) * C_ + co0 + ncol] =
                            f2bf(acc[mi][ni][r] + bias[co0 + ncol]);
                    }
        } else {
#pragma unroll
            for (int mi = 0; mi < 4; ++mi)
#pragma unroll
                for (int ni = 0; ni < 4; ++ni) {
                    int ncol = wn * 64 + ni * 16 + l15;
                    float bb = bias[co0 + ncol];
                    ushort4 pk;
                    pk.x = f2bf(acc[mi][ni][0] + bb);
                    pk.y = f2bf(acc[mi][ni][1] + bb);
                    pk.z = f2bf(acc[mi][ni][2] + bb);
                    pk.w = f2bf(acc[mi][ni][3] + bb);
                    int jb = j0 + wm * 64 + mi * 16 + quad * 4;
                    *(ushort4*)&Vg[((size_t)b * C_ + co0 + ncol) * N_ + jb] = pk;
                }
        }
    });
}

// ------------- GEMM1 (R9): P = exp(Q K^T * scale - 12), rowsum partials -----
// 256x256 tile, 8 waves (2M x 4N), BK=32, ring-4 LDS, counted vmcnt.
// XCD rect swizzle: each XCD owns a 4(Q-tile) x 8(K-tile) rectangle per
// round -> staged Q panel (1 MB) + K panel (2 MB) fit the XCD's 4 MB L2.
__global__ __launch_bounds__(512, 2) void gemm_qk_exp(const unsigned short* __restrict__ Qt,
                                                      const unsigned short* __restrict__ Kt,
                                                      unsigned short* __restrict__ P,
                                                      float* __restrict__ psum) {
    extern __shared__ unsigned short sm[];   // 4 bufs x (A 8192 | B 8192) ushorts
    // XCD rectangle remap (1024 blocks = 4 rounds of 256; xcd = lin & 7)
    int lin = blockIdx.x + 16 * blockIdx.y + 256 * blockIdx.z;
    int xcd = lin & 7;
    int i4  = lin >> 3;                 // 0..127
    int idx = i4 & 31;                  // position within the XCD's 32 blocks
    int b   = i4 >> 5;                  // round = batch
    int rq  = xcd & 3, rk = xcd >> 2;   // rect id == xcd
    int j0  = (rq * 4 + (idx & 3)) * 256;
    int ky  = rk * 8 + (idx >> 2);
    int kc0 = ky * 256;
    const unsigned short* A  = Qt + ((size_t)b * N_ + j0) * C_;
    const unsigned short* Bm = Kt + ((size_t)b * N_ + kc0) * C_;

    int t = threadIdx.x;
    int w = t >> 6, lane = t & 63, l15 = lane & 15, quad = lane >> 4;
    int wm = w >> 2, wn = w & 3;
    int srow = lane >> 2;                              // row within 16-row seg
    int sch  = (((lane & 3) ^ ((lane >> 3) & 3))) * 8; // swizzled source chunk (elems)
    int slotq = (quad ^ ((l15 >> 1) & 3)) * 8;         // frag-read slot (elems)

    f32x4 acc[8][4] = {};

    const int NT = 16;                       // K=512 / BK=32
    // prologue: stage tiles 0..2 into bufs 0..2 (12 loads/thread)
#pragma unroll
    for (int tt = 0; tt < 3; ++tt) {
        unsigned short* dst = sm + (tt << 14);
        size_t k0 = (size_t)tt << 5;
#pragma unroll
        for (int i = 0; i < 2; ++i) {
            int seg = w * 2 + i;
            size_t row = (size_t)seg * 16 + srow;
            async16(&A [row * C_ + k0 + sch], dst + seg * 512);
            async16(&Bm[row * C_ + k0 + sch], dst + 8192 + seg * 512);
        }
    }
    __builtin_amdgcn_s_waitcnt(0x3F78);      // vmcnt(8): tile 0 landed
    __builtin_amdgcn_s_barrier();

    for (int tt = 0; tt < NT; ++tt) {
        const unsigned short* bp = sm + ((tt & 3) << 14);
        unsigned short* stg = sm + (((tt + 3) & 3) << 14);
        const bool dostage = (tt + 3 < NT);
        size_t k0n = (size_t)(tt + 3) << 5;
        // ---- phase A: read B-frags + A-frags mi0..3, stage A half of t+3
        bf16x8 bfr[4], af[4];
#pragma unroll
        for (int ni = 0; ni < 4; ++ni)
            bfr[ni] = *(const bf16x8*)&bp[8192 + (wn * 64 + ni * 16 + l15) * 32 + slotq];
#pragma unroll
        for (int mi = 0; mi < 4; ++mi)
            af[mi] = *(const bf16x8*)&bp[(wm * 128 + mi * 16 + l15) * 32 + slotq];
        if (dostage) {
#pragma unroll
            for (int i = 0; i < 2; ++i) {
                int seg = w * 2 + i;
                size_t row = (size_t)seg * 16 + srow;
                async16(&A[row * C_ + k0n + sch], stg + seg * 512);
            }
        }
        __builtin_amdgcn_s_barrier();
        __builtin_amdgcn_s_setprio(1);
#pragma unroll
        for (int mi = 0; mi < 4; ++mi)
#pragma unroll
            for (int ni = 0; ni < 4; ++ni)
                acc[mi][ni] = MFMA16(af[mi], bfr[ni], acc[mi][ni]);
        __builtin_amdgcn_s_setprio(0);
        __builtin_amdgcn_s_barrier();
        // ---- phase B: read A-frags mi4..7, stage B half of t+3
#pragma unroll
        for (int mi = 0; mi < 4; ++mi)
            af[mi] = *(const bf16x8*)&bp[(wm * 128 + (mi + 4) * 16 + l15) * 32 + slotq];
        if (dostage) {
#pragma unroll
            for (int i = 0; i < 2; ++i) {
                int seg = w * 2 + i;
                size_t row = (size_t)seg * 16 + srow;
                async16(&Bm[row * C_ + k0n + sch], stg + 8192 + seg * 512);
            }
        }
        __builtin_amdgcn_s_barrier();
        __builtin_amdgcn_s_setprio(1);
#pragma unroll
        for (int mi = 0; mi < 4; ++mi)
#pragma unroll
            for (int ni = 0; ni < 4; ++ni)
                acc[4 + mi][ni] = MFMA16(af[mi], bfr[ni], acc[4 + mi][ni]);
        __builtin_amdgcn_s_setprio(0);
        // ---- tile boundary: counted wait for tile tt+1's staging
        if (tt + 1 < NT) {
            if (tt < NT - 3)       __builtin_amdgcn_s_waitcnt(0x3F78); // vmcnt(8)
            else if (tt == NT - 3) __builtin_amdgcn_s_waitcnt(0x3F74); // vmcnt(4)
            else                   __builtin_amdgcn_s_waitcnt(0x3F70); // vmcnt(0)
            __builtin_amdgcn_s_barrier();
        }
    }

    // ---- epilogue: exp + P store + per-wave rowsum partials
#pragma unroll
    for (int mi = 0; mi < 8; ++mi) {
        float rs[4] = {0.f, 0.f, 0.f, 0.f};
#pragma unroll
        for (int ni = 0; ni < 4; ++ni) {
            int ncol = kc0 + wn * 64 + ni * 16 + l15;
#pragma unroll
            for (int r = 0; r < 4; ++r) {
                int mrow = j0 + wm * 128 + mi * 16 + quad * 4 + r;
                float p = __expf(acc[mi][ni][r] * SCALE - ESHIFT);
                rs[r] += p;
                P[((size_t)b * N_ + mrow) * N_ + ncol] = f2bf(p);
            }
        }
#pragma unroll
        for (int r = 0; r < 4; ++r) {
            float v = rs[r];
            v += __shfl_xor(v, 1);
            v += __shfl_xor(v, 2);
            v += __shfl_xor(v, 4);
            v += __shfl_xor(v, 8);
            if (l15 == 0)
                psum[(size_t)(wn * 16 + ky) * 16384 +
                     (size_t)b * N_ + j0 + wm * 128 + mi * 16 + quad * 4 + r] = v;
        }
    }
}

// ------------- GEMM2 (R9): O = (P V) / l -> AObf[b][n][c] bf16 --------------
// 256x128 tile, 8 waves (4M x 2N, wave out 64x64), BK=32, ring-4 LDS
// (96 KiB), counted vmcnt(6), 2 barriers/tile, K=4096 (128 tiles, no tail).
// XCD swizzle: the 4 ct-blocks sharing a 2 MB P-tile land on one XCD.
__global__ __launch_bounds__(512, 2) void gemm_pv(const unsigned short* __restrict__ P,
                                                  const unsigned short* __restrict__ Vg,
                                                  const float* __restrict__ psum,
                                                  unsigned short* __restrict__ ao) {
    extern __shared__ unsigned short sm[];   // 4 bufs x (A 8192 | B 4096) ushorts
    __shared__ float linv[256];
    int lin = blockIdx.x;                    // 0..255
    int xcd = lin & 7;
    int i4  = lin >> 3;                      // 0..31
    int ct  = i4 & 3;
    int grp = xcd + 8 * (i4 >> 2);           // 0..63
    int b = grp & 3, qtile = grp >> 2;
    int j0 = qtile * 256, co0 = ct * 128;
    int t = threadIdx.x;
    int w = t >> 6, lane = t & 63, l15 = lane & 15, quad = lane >> 4;
    int wm = w >> 1, wn = w & 1;
    int srow = lane >> 2;
    int sch  = ((lane & 3) ^ ((lane >> 3) & 3)) * 8;
    int slotq = (quad ^ ((l15 >> 1) & 3)) * 8;
    const unsigned short* A  = P  + ((size_t)b * N_ + j0) * N_;
    const unsigned short* Bm = Vg + ((size_t)b * C_ + co0) * N_;
    f32x4 acc[4][4] = {};
    const int NT = 128;                      // K = 4096 / 32
    // prologue: tiles 0..2 -> bufs 0..2 (9 loads/thread)
#pragma unroll
    for (int tt = 0; tt < 3; ++tt) {
        unsigned short* dst = sm + tt * 12288;
        size_t k0 = (size_t)tt << 5;
#pragma unroll
        for (int i = 0; i < 2; ++i) {
            int seg = w * 2 + i;
            size_t row = (size_t)seg * 16 + srow;
            async16(&A[row * N_ + k0 + sch], dst + seg * 512);
        }
        {
            size_t row = (size_t)w * 16 + srow;
            async16(&Bm[row * N_ + k0 + sch], dst + 8192 + w * 512);
        }
    }
    // linv (psum reduction) overlaps the prologue loads
    if (t < 256) {
        size_t q = (size_t)b * N_ + j0 + t;
        float s = 0.f;
#pragma unroll
        for (int i = 0; i < 64; ++i) s += psum[(size_t)i * 16384 + q];
        linv[t] = 1.f / s;
    }
    __builtin_amdgcn_s_waitcnt(0x3F76);      // vmcnt(6): tile 0 landed
    __builtin_amdgcn_s_barrier();
    for (int tt = 0; tt < NT; ++tt) {
        const unsigned short* bp = sm + (tt & 3) * 12288;
        bf16x8 af[4], bfr[4];
#pragma unroll
        for (int mi = 0; mi < 4; ++mi)
            af[mi] = *(const bf16x8*)&bp[(wm * 64 + mi * 16 + l15) * 32 + slotq];
#pragma unroll
        for (int ni = 0; ni < 4; ++ni)
            bfr[ni] = *(const bf16x8*)&bp[8192 + (wn * 64 + ni * 16 + l15) * 32 + slotq];
        if (tt + 3 < NT) {
            unsigned short* stg = sm + ((tt + 3) & 3) * 12288;
            size_t k0n = (size_t)(tt + 3) << 5;
#pragma unroll
            for (int i = 0; i < 2; ++i) {
                int seg = w * 2 + i;
                size_t row = (size_t)seg * 16 + srow;
                async16(&A[row * N_ + k0n + sch], stg + seg * 512);
            }
            {
                size_t row = (size_t)w * 16 + srow;
                async16(&Bm[row * N_ + k0n + sch], stg + 8192 + w * 512);
            }
        }
        __builtin_amdgcn_s_barrier();
        __builtin_amdgcn_s_setprio(1);
#pragma unroll
        for (int mi = 0; mi < 4; ++mi)
#pragma unroll
            for (int ni = 0; ni < 4; ++ni)
                acc[mi][ni] = MFMA16(af[mi], bfr[ni], acc[mi][ni]);
        __builtin_amdgcn_s_setprio(0);
        if (tt + 1 < NT) {
            if (tt + 3 < NT)      __builtin_amdgcn_s_waitcnt(0x3F76); // vmcnt(6)
            else if (tt + 2 < NT) __builtin_amdgcn_s_waitcnt(0x3F73); // vmcnt(3)
            else                  __builtin_amdgcn_s_waitcnt(0x3F70); // vmcnt(0)
            __builtin_amdgcn_s_barrier();
        }
    }
    // epilogue: scale by 1/l and store
#pragma unroll
    for (int mi = 0; mi < 4; ++mi)
#pragma unroll
        for (int ni = 0; ni < 4; ++ni)
#pragma unroll
            for (int r = 0; r < 4; ++r) {
                int mrow = wm * 64 + mi * 16 + quad * 4 + r;
                int ncol = wn * 64 + ni * 16 + l15;
                ao[((size_t)b * N_ + j0 + mrow) * C_ + co0 + ncol] =
                    f2bf(acc[mi][ni][r] * linv[mrow]);
            }
}

// ------------- final projection + residual: grid (32, 4, 4) -----------------
__global__ __launch_bounds__(256) void gemm_resid(const unsigned short* __restrict__ AObf,
                                                  const unsigned short* __restrict__ Wo,
                                                  const float* __restrict__ bo,
                                                  const float* __restrict__ xres,
                                                  float* __restrict__ out) {
    int b = blockIdx.z, j0 = blockIdx.x * 128, co0 = blockIdx.y * 128;
    const unsigned short* A = AObf + ((size_t)b * N_ + j0) * C_;
    const unsigned short* B = Wo + (size_t)co0 * C_;
    gemm_core(A, B, C_, C_, C_,
        [&](f32x4 (&acc)[4][4], int wm, int wn, int l15, int quad) {
#pragma unroll
        for (int mi = 0; mi < 4; ++mi)
#pragma unroll
            for (int ni = 0; ni < 4; ++ni) {
                int ncol = wn * 64 + ni * 16 + l15;
                int jb = j0 + wm * 64 + mi * 16 + quad * 4;
                size_t o = ((size_t)b * C_ + co0 + ncol) * N_ + jb;
                float bb = bo[co0 + ncol];
                float4 xr = *(const float4*)&xres[o];
                float4 ov;
                ov.x = acc[mi][ni][0] + bb + xr.x;
                ov.y = acc[mi][ni][1] + bb + xr.y;
                ov.z = acc[mi][ni][2] + bb + xr.z;
                ov.w = acc[mi][ni][3] + bb + xr.w;
                *(float4*)&out[o] = ov;
            }
    });
}

// ------------- FALLBACK: R4 flash attention (if ws too small) ---------------
__global__ __launch_bounds__(256, 1) void flash_attn(const unsigned short* __restrict__ Qt,
                                                     const unsigned short* __restrict__ Kt,
                                                     const unsigned short* __restrict__ Vg,
                                                     unsigned short* __restrict__ part,
                                                     float* __restrict__ lbuf,
                                                     int nsplit) {
    extern __shared__ unsigned short smem[];
    unsigned short* Kl = smem;
    unsigned short* Vl = smem + 32768;
    unsigned short* Pl = smem + 65536;

    int flat = blockIdx.x;
    int qblk, b, s;
    if (nsplit == 2) { s = flat & 1; b = (flat >> 1) & 3; qblk = flat >> 3; }
    else             { s = 0;        b = flat & 3;        qblk = flat >> 2; }
    int q0 = qblk * 128;
    int t = threadIdx.x, w = t >> 6, lane = t & 63, l15 = lane & 15, quad = lane >> 4;
    int klen = N_ / nsplit, kbeg = s * klen, nkt = klen / 32;
    int xr = l15 & 7;

    const unsigned short* Kbase = Kt + (size_t)b * N_ * C_;
    const unsigned short* Vbase = Vg + (size_t)b * C_ * N_;

    bf16x8 qa[2][16];
#pragma unroll
    for (int u = 0; u < 2; ++u) {
        const unsigned short* qb =
            Qt + ((size_t)b * N_ + q0 + w * 32 + u * 16 + l15) * C_ + quad * 8;
#pragma unroll
        for (int ck = 0; ck < 16; ++ck) qa[u][ck] = *(const bf16x8*)(qb + ck * 32);
    }

    f32x4 o[2][32] = {};
    float lrow[2][4] = {};

    {
        int k0 = kbeg;
#pragma unroll
        for (int i = 0; i < 8; ++i) {
            int r = w * 8 + i;
            async16(Kbase + (size_t)(k0 + r) * C_ + ((lane ^ (r & 7)) * 8), Kl + r * 512);
        }
#pragma unroll
        for (int i = 0; i < 8; ++i) {
            int idx = w * 8 + i, kc = idx >> 3, cb = idx & 7;
            async16(Vbase + (size_t)(cb * 64 + lane) * N_ + k0 + kc * 8,
                    Vl + (kc * 512 + cb * 64) * 8);
        }
    }

    for (int kt = 0; kt < nkt; ++kt) {
        int cur = kt & 1, nxt = cur ^ 1;
        __builtin_amdgcn_s_waitcnt(0x3F70);
        __syncthreads();
        if (kt + 1 < nkt) {
            int k0 = kbeg + (kt + 1) * 32;
#pragma unroll
            for (int i = 0; i < 8; ++i) {
                int r = w * 8 + i;
                async16(Kbase + (size_t)(k0 + r) * C_ + ((lane ^ (r & 7)) * 8),
                        Kl + nxt * 16384 + r * 512);
            }
#pragma unroll
            for (int i = 0; i < 8; ++i) {
                int idx = w * 8 + i, kc = idx >> 3, cb = idx & 7;
                async16(Vbase + (size_t)(cb * 64 + lane) * N_ + k0 + kc * 8,
                        Vl + nxt * 16384 + (kc * 512 + cb * 64) * 8);
            }
        }
        const unsigned short* Kc = Kl + cur * 16384;
        f32x4 s00 = {}, s01 = {}, s10 = {}, s11 = {};
#pragma unroll
        for (int ck = 0; ck < 16; ++ck) {
            int slot = (ck * 4 + quad) ^ xr;
            bf16x8 b0 = *(const bf16x8*)&Kc[l15 * 512 + slot * 8];
            bf16x8 b1 = *(const bf16x8*)&Kc[(16 + l15) * 512 + slot * 8];
            s00 = MFMA16(qa[0][ck], b0, s00);
            s10 = MFMA16(qa[1][ck], b0, s10);
            s01 = MFMA16(qa[0][ck], b1, s01);
            s11 = MFMA16(qa[1][ck], b1, s11);
        }
        unsigned short* pb = &Pl[w * 1152];
#pragma unroll
        for (int r = 0; r < 4; ++r) {
            float p00 = __expf(s00[r] * SCALE - ESHIFT);
            float p01 = __expf(s01[r] * SCALE - ESHIFT);
            float p10 = __expf(s10[r] * SCALE - ESHIFT);
            float p11 = __expf(s11[r] * SCALE - ESHIFT);
            lrow[0][r] += p00 + p01;
            lrow[1][r] += p10 + p11;
            int row0 = (quad * 4 + r) * 36;
            int row1 = (16 + quad * 4 + r) * 36;
            pb[row0 + l15]      = f2bf(p00);
            pb[row0 + 16 + l15] = f2bf(p01);
            pb[row1 + l15]      = f2bf(p10);
            pb[row1 + 16 + l15] = f2bf(p11);
        }
        __builtin_amdgcn_s_waitcnt(0xC07F);
        bf16x8 pa0 = *(const bf16x8*)&Pl[w * 1152 + l15 * 36 + quad * 8];
        bf16x8 pa1 = *(const bf16x8*)&Pl[w * 1152 + (16 + l15) * 36 + quad * 8];
        const unsigned short* Vc = Vl + cur * 16384;
#pragma unroll
        for (int cf = 0; cf < 32; ++cf) {
            bf16x8 vb = *(const bf16x8*)&Vc[(quad * 512 + cf * 16 + l15) * 8];
            o[0][cf] = MFMA16(pa0, vb, o[0][cf]);
            o[1][cf] = MFMA16(pa1, vb, o[1][cf]);
        }
    }
#pragma unroll
    for (int u = 0; u < 2; ++u)
#pragma unroll
        for (int r = 0; r < 4; ++r) {
            float l = lrow[u][r];
            l += __shfl_xor(l, 1);
            l += __shfl_xor(l, 2);
            l += __shfl_xor(l, 4);
            l += __shfl_xor(l, 8);
            lrow[u][r] = l;
        }
    size_t pbase = (size_t)(s * B_ + b) * N_;
#pragma unroll
    for (int u = 0; u < 2; ++u)
#pragma unroll
        for (int cf = 0; cf < 32; ++cf)
#pragma unroll
            for (int r = 0; r < 4; ++r) {
                int q = q0 + w * 32 + u * 16 + quad * 4 + r;
                part[(pbase + q) * C_ + cf * 16 + l15] = f2bf(o[u][cf][r]);
            }
    if (l15 == 0) {
#pragma unroll
        for (int u = 0; u < 2; ++u)
#pragma unroll
            for (int r = 0; r < 4; ++r) {
                int q = q0 + w * 32 + u * 16 + quad * 4 + r;
                lbuf[pbase + q] = lrow[u][r];
            }
    }
}

__global__ __launch_bounds__(256) void attn_combine(const unsigned short* __restrict__ part,
                                                    const float* __restrict__ lbuf,
                                                    unsigned short* __restrict__ ao,
                                                    int nsplit) {
    size_t idx = (size_t)blockIdx.x * 256 + threadIdx.x;
    int cu = (int)(idx & 63);
    size_t row = idx >> 6;
    float l = lbuf[row];
    union { uint4 v; unsigned short u[8]; } p1, p2, outv;
    p1.v = *(const uint4*)&part[row * C_ + cu * 8];
    if (nsplit == 2) {
        l += lbuf[(size_t)B_ * N_ + row];
        p2.v = *(const uint4*)&part[((size_t)B_ * N_ + row) * C_ + cu * 8];
    } else {
        p2.v = make_uint4(0, 0, 0, 0);
    }
    float inv = 1.f / l;
#pragma unroll
    for (int j = 0; j < 8; ++j)
        outv.u[j] = f2bf((bf2f(p1.u[j]) + bf2f(p2.u[j])) * inv);
    *(uint4*)&ao[row * C_ + cu * 8] = outv.v;
}

// ---------------------------------------------------------------------------
extern "C" void kernel_launch(void* const* d_in, const int* in_sizes, int n_in,
                              void* d_out, int out_size, void* d_ws, size_t ws_size,
                              hipStream_t stream) {
    const float* x   = (const float*)d_in[0];
    const float* gam = (const float*)d_in[1];
    const float* bet = (const float*)d_in[2];
    const float* wq  = (const float*)d_in[3];
    const float* bq  = (const float*)d_in[4];
    const float* wk  = (const float*)d_in[5];
    const float* bk  = (const float*)d_in[6];
    const float* wv  = (const float*)d_in[7];
    const float* bv  = (const float*)d_in[8];
    const float* wo  = (const float*)d_in[9];
    const float* bo  = (const float*)d_in[10];
    float* out = (float*)d_out;

    char* ws = (char*)d_ws;
    const size_t SZH = (size_t)B_ * N_ * C_ * 2;          // 16 MiB bf16 tensor
    const size_t OFF_HT = 4096;
    const size_t OFF_QT = OFF_HT + SZH;
    const size_t OFF_KT = OFF_QT + SZH;
    const size_t OFF_VG = OFF_KT + SZH;
    const size_t OFF_WB = OFF_VG + SZH;
    const size_t OFF_X  = OFF_WB + 2097152;               // 69,210,112
    float*          part0 = (float*)ws;                   // gn partial sums
    unsigned short* Ht    = (unsigned short*)(ws + OFF_HT);
    unsigned short* Qt    = (unsigned short*)(ws + OFF_QT);
    unsigned short* Kt    = (unsigned short*)(ws + OFF_KT);
    unsigned short* Vg    = (unsigned short*)(ws + OFF_VG);
    unsigned short* Wb    = (unsigned short*)(ws + OFF_WB);
    unsigned short* AObf  = Ht;  // Ht dead after projections

    // Path A: materialized-P two-GEMM attention.
    const size_t SZPSUM = 64ull * 16384 * 4;              // 4 MiB
    const size_t SZP    = (size_t)B_ * N_ * N_ * 2;       // 128 MiB
    float*          psum = (float*)(ws + OFF_X);
    unsigned short* P    = (unsigned short*)(ws + OFF_X + SZPSUM);
    size_t needA = OFF_X + SZPSUM + SZP;

    // Path B (fallback): R4 flash.
    float*          lbuf = (float*)(ws + OFF_X);
    unsigned short* partb = (unsigned short*)(ws + OFF_X + 262144);
    size_t needB2 = OFF_X + 262144 + 2 * SZH;

    gn_partial<<<512, 256, 0, stream>>>(x, part0);
    gn_apply<<<dim3(64, 8, B_), 256, 0, stream>>>(x, gam, bet, part0, Ht);
    wconv<<<4096, 256, 0, stream>>>(wq, wk, wv, wo, Wb);
    gemm_qkv<<<dim3(32, 12, B_), 256, 0, stream>>>(Ht, Wb, bq, bk, bv, Qt, Kt, Vg);

    if (ws_size >= needA) {
        const int QK_LDS = 131072;   // 4 ring bufs x 32 KiB
        (void)hipFuncSetAttribute((const void*)gemm_qk_exp,
                                  hipFuncAttributeMaxDynamicSharedMemorySize, QK_LDS);
        gemm_qk_exp<<<dim3(16, 16, B_), 512, QK_LDS, stream>>>(Qt, Kt, P, psum);
        const int PV_LDS = 98304;    // 4 ring bufs x 24 KiB
        (void)hipFuncSetAttribute((const void*)gemm_pv,
                                  hipFuncAttributeMaxDynamicSharedMemorySize, PV_LDS);
        gemm_pv<<<256, 512, PV_LDS, stream>>>(P, Vg, psum, AObf);
    } else {
        int nsplit = (ws_size >= needB2) ? 2 : 1;
        const int FLASH_LDS = 140288;
        (void)hipFuncSetAttribute((const void*)flash_attn,
                                  hipFuncAttributeMaxDynamicSharedMemorySize, FLASH_LDS);
        flash_attn<<<dim3(32 * B_ * nsplit), 256, FLASH_LDS, stream>>>(Qt, Kt, Vg, partb, lbuf, nsplit);
        attn_combine<<<4096, 256, 0, stream>>>(partb, lbuf, AObf, nsplit);
    }
    gemm_resid<<<dim3(32, 4, B_), 256, 0, stream>>>(AObf, Wb + 786432, bo, x, out);
}

// Round 3
// 325.360 us; speedup vs baseline: 1.1380x; 1.0505x over previous
//
#include <hip/hip_runtime.h>

// ---------------------------------------------------------------------------
// AttnBlock: GroupNorm -> q,k,v 1x1 conv -> softmax(QK^T/sqrt(c)) V -> out
// conv -> residual.  b=4, c=512, h=w=64 (n=4096), 32 groups.
// R10: barrier-minimal deep pipelines.  qk/pv keep the ring-4 LDS + counted
//      vmcnt, but ALL intra-tile barriers are removed (ring-4 makes them
//      correctness-redundant: stage target (tt+3)&3 == (tt-1)&3 is only
//      reused after the tt-1 -> tt boundary barrier; frag reads are
//      wave-private VGPR deps).  One vmcnt(counted)+s_barrier per K-tile.
//      This breaks the 8-wave lockstep so LDS-port and MFMA-pipe overlap.
//      Epilogue exp folded to a single fma+v_exp (exp2f).
// ---------------------------------------------------------------------------

typedef __attribute__((ext_vector_type(8))) short bf16x8;   // 8 bf16 (4 VGPR)
typedef __attribute__((ext_vector_type(4))) float f32x4;    // MFMA acc frag

#define MFMA16(a, b, c) __builtin_amdgcn_mfma_f32_16x16x32_bf16((a), (b), (c), 0, 0, 0)

#define B_   4
#define C_   512
#define N_   4096
#define SCALE 0.044194173824159216f  // 1/sqrt(512)
#define ESHIFT 12.0f                 // uniform exp shift (overflow insurance)
#define SC2   0.06376297465050853f   // SCALE * log2(e)
#define ES2   17.312340490667562f    // ESHIFT * log2(e)

__device__ __forceinline__ unsigned short f2bf(float f) {
    union { float f; unsigned int u; } v; v.f = f;
    unsigned int r = (v.u + 0x7fffu + ((v.u >> 16) & 1u)) >> 16;  // RNE
    return (unsigned short)r;
}
__device__ __forceinline__ float bf2f(unsigned short s) {
    union { unsigned int u; float f; } v; v.u = ((unsigned int)s) << 16;
    return v.f;
}

// async 16B global -> LDS (lane i lands at lds + i*16)
__device__ __forceinline__ void async16(const unsigned short* g, unsigned short* l) {
    __builtin_amdgcn_global_load_lds((const __attribute__((address_space(1))) unsigned int*)g,
                                     (__attribute__((address_space(3))) unsigned int*)l,
                                     16, 0, 0);
}

// ---------------- GroupNorm partial sums: 512 blocks (4 per group) ----------
__global__ __launch_bounds__(256) void gn_partial(const float* __restrict__ x,
                                                  float* __restrict__ part) {
    int blk = blockIdx.x;           // 0..511
    int gid = blk >> 2, qtr = blk & 3;
    const float4* base = (const float4*)(x + (size_t)gid * 65536) + qtr * 4096;
    float s = 0.f, ss = 0.f;
    for (int i = threadIdx.x; i < 4096; i += 256) {
        float4 v = base[i];
        s  += v.x + v.y + v.z + v.w;
        ss += v.x * v.x + v.y * v.y + v.z * v.z + v.w * v.w;
    }
    __shared__ float red[512];
    int t = threadIdx.x;
    red[t] = s; red[256 + t] = ss;
    __syncthreads();
    for (int st = 128; st > 0; st >>= 1) {
        if (t < st) { red[t] += red[t + st]; red[256 + t] += red[256 + t + st]; }
        __syncthreads();
    }
    if (t == 0) { part[blk] = red[0]; part[512 + blk] = red[256]; }
}

// ------------- GroupNorm apply + transpose -> Ht[b][n][c] bf16 --------------
__global__ __launch_bounds__(256) void gn_apply(const float* __restrict__ x,
                                                const float* __restrict__ gamma,
                                                const float* __restrict__ beta,
                                                const float* __restrict__ part,
                                                unsigned short* __restrict__ ht) {
    __shared__ float tile[64][65];
    __shared__ float mrs[4][2];
    int j0 = blockIdx.x * 64, c0 = blockIdx.y * 64, b = blockIdx.z;
    int t = threadIdx.x;
    if (t < 4) {
        int gid = b * 32 + (c0 >> 4) + t;
        float s = 0.f, ss = 0.f;
#pragma unroll
        for (int q = 0; q < 4; ++q) { s += part[gid * 4 + q]; ss += part[512 + gid * 4 + q]; }
        float mean = s * (1.f / 65536.f);
        float var  = ss * (1.f / 65536.f) - mean * mean;
        mrs[t][0] = mean;
        mrs[t][1] = rsqrtf(var + 1e-6f);
    }
    __syncthreads();
#pragma unroll
    for (int i = 0; i < 16; ++i) {
        int lid = i * 256 + t;
        int cl = lid >> 6, jl = lid & 63;
        int c = c0 + cl;
        float v = x[((size_t)b * C_ + c) * N_ + j0 + jl];
        tile[cl][jl] = (v - mrs[cl >> 4][0]) * mrs[cl >> 4][1] * gamma[c] + beta[c];
    }
    __syncthreads();
#pragma unroll
    for (int i = 0; i < 16; ++i) {
        int lid = i * 256 + t;
        int jl = lid >> 6, cl = lid & 63;
        ht[((size_t)b * N_ + j0 + jl) * C_ + c0 + cl] = f2bf(tile[cl][jl]);
    }
}

// ------------- convert the 4 weight matrices to bf16 ------------------------
__global__ __launch_bounds__(256) void wconv(const float* __restrict__ wq,
                                             const float* __restrict__ wk,
                                             const float* __restrict__ wv,
                                             const float* __restrict__ wo,
                                             unsigned short* __restrict__ dst) {
    size_t i = (size_t)blockIdx.x * 256 + threadIdx.x;  // 4*512*512 total
    int m = (int)(i >> 18);
    size_t off = i & 262143;
    const float* src = (m == 0) ? wq : (m == 1) ? wk : (m == 2) ? wv : wo;
    dst[i] = f2bf(src[off]);
}

// ------------- 128x128xK MFMA GEMM core: dbuf + XOR-swizzled LDS ------------
template <typename EPI>
__device__ __forceinline__ void gemm_core(const unsigned short* __restrict__ Abase,
                                          const unsigned short* __restrict__ Bbase,
                                          size_t lda, size_t ldb, int K, EPI epi) {
    __shared__ unsigned short hl[2][128 * 64];
    __shared__ unsigned short wl[2][128 * 64];
    int t = threadIdx.x;
    int wv = t >> 6, lane = t & 63, l15 = lane & 15, quad = lane >> 4;
    int wm = wv & 1, wn = wv >> 1;
    int srow = lane >> 3;                    // row within 8-row seg
    int sch  = ((lane & 7) ^ srow) * 8;      // XOR-swizzled chunk offset
    int xr = l15 & 7;
    f32x4 acc[4][4] = {};
    // prologue: stage tile 0 into buf 0
#pragma unroll
    for (int i = 0; i < 4; ++i) {
        int seg = wv * 4 + i;
        size_t row = seg * 8 + srow;
        async16(&Abase[row * lda + sch], &hl[0][seg * 512]);
        async16(&Bbase[row * ldb + sch], &wl[0][seg * 512]);
    }
    int nk = K >> 6;
    for (int k = 0; k < nk; ++k) {
        int cur = k & 1;
        __builtin_amdgcn_s_waitcnt(0x3F70);  // vmcnt(0)
        __syncthreads();
        if (k + 1 < nk) {                    // prefetch k+1 (post-barrier: buf free)
            int k0 = (k + 1) << 6;
#pragma unroll
            for (int i = 0; i < 4; ++i) {
                int seg = wv * 4 + i;
                size_t row = seg * 8 + srow;
                async16(&Abase[row * lda + k0 + sch], &hl[cur ^ 1][seg * 512]);
                async16(&Bbase[row * ldb + k0 + sch], &wl[cur ^ 1][seg * 512]);
            }
        }
#pragma unroll
        for (int kk = 0; kk < 2; ++kk) {
            int sl = (((kk << 2) + quad) ^ xr) * 8;
            bf16x8 af[4], bfr[4];
#pragma unroll
            for (int mi = 0; mi < 4; ++mi)
                af[mi] = *(const bf16x8*)&hl[cur][(wm * 64 + mi * 16 + l15) * 64 + sl];
#pragma unroll
            for (int ni = 0; ni < 4; ++ni)
                bfr[ni] = *(const bf16x8*)&wl[cur][(wn * 64 + ni * 16 + l15) * 64 + sl];
#pragma unroll
            for (int mi = 0; mi < 4; ++mi)
#pragma unroll
                for (int ni = 0; ni < 4; ++ni)
                    acc[mi][ni] = MFMA16(af[mi], bfr[ni], acc[mi][ni]);
        }
    }
    epi(acc, wm, wn, l15, quad);
}

// ------------- fused QKV projection: grid (32, 12, 4) -----------------------
__global__ __launch_bounds__(256) void gemm_qkv(const unsigned short* __restrict__ Ht,
                                                const unsigned short* __restrict__ Wb,
                                                const float* __restrict__ bq,
                                                const float* __restrict__ bk,
                                                const float* __restrict__ bv,
                                                unsigned short* __restrict__ Qt,
                                                unsigned short* __restrict__ Kt,
                                                unsigned short* __restrict__ Vg) {
    int b = blockIdx.z, j0 = blockIdx.x * 128;
    int ct = blockIdx.y;                 // 0..11
    int slab = ct >> 2, co0 = (ct & 3) * 128;
    const unsigned short* A = Ht + ((size_t)b * N_ + j0) * C_;
    const unsigned short* B = Wb + (size_t)slab * C_ * C_ + (size_t)co0 * C_;
    const float* bias = (slab == 0) ? bq : (slab == 1) ? bk : bv;
    unsigned short* outqk = (slab == 0) ? Qt : Kt;
    gemm_core(A, B, C_, C_, C_,
        [&](f32x4 (&acc)[4][4], int wm, int wn, int l15, int quad) {
        if (slab < 2) {
#pragma unroll
            for (int mi = 0; mi < 4; ++mi)
#pragma unroll
                for (int ni = 0; ni < 4; ++ni)
#pragma unroll
                    for (int r = 0; r < 4; ++r) {
                        int mrow = wm * 64 + mi * 16 + quad * 4 + r;
                        int ncol = wn * 64 + ni * 16 + l15;
                        outqk[((size_t)b * N_ + j0 + mrow) * C_ + co0 + ncol] =
                            f2bf(acc[mi][ni][r] + bias[co0 + ncol]);
                    }
        } else {
#pragma unroll
            for (int mi = 0; mi < 4; ++mi)
#pragma unroll
                for (int ni = 0; ni < 4; ++ni) {
                    int ncol = wn * 64 + ni * 16 + l15;
                    float bb = bias[co0 + ncol];
                    ushort4 pk;
                    pk.x = f2bf(acc[mi][ni][0] + bb);
                    pk.y = f2bf(acc[mi][ni][1] + bb);
                    pk.z = f2bf(acc[mi][ni][2] + bb);
                    pk.w = f2bf(acc[mi][ni][3] + bb);
                    int jb = j0 + wm * 64 + mi * 16 + quad * 4;
                    *(ushort4*)&Vg[((size_t)b * C_ + co0 + ncol) * N_ + jb] = pk;
                }
        }
    });
}

// ------------- GEMM1 (R10): P = exp(Q K^T * scale - 12), rowsum partials ----
// 256x256 tile, 8 waves (2M x 4N), BK=32, ring-4 LDS, counted vmcnt.
// ONE vmcnt+barrier per K-tile; no intra-tile barriers (ring-4 makes the
// stage target (tt+3)&3 == (tt-1)&3 safe after the boundary barrier; frag
// reads are wave-private).  XCD rect swizzle for L2-resident panels.
__global__ __launch_bounds__(512, 2) void gemm_qk_exp(const unsigned short* __restrict__ Qt,
                                                      const unsigned short* __restrict__ Kt,
                                                      unsigned short* __restrict__ P,
                                                      float* __restrict__ psum) {
    extern __shared__ unsigned short sm[];   // 4 bufs x (A 8192 | B 8192) ushorts
    // XCD rectangle remap (1024 blocks = 4 rounds of 256; xcd = lin & 7)
    int lin = blockIdx.x + 16 * blockIdx.y + 256 * blockIdx.z;
    int xcd = lin & 7;
    int i4  = lin >> 3;                 // 0..127
    int idx = i4 & 31;                  // position within the XCD's 32 blocks
    int b   = i4 >> 5;                  // round = batch
    int rq  = xcd & 3, rk = xcd >> 2;   // rect id == xcd
    int j0  = (rq * 4 + (idx & 3)) * 256;
    int ky  = rk * 8 + (idx >> 2);
    int kc0 = ky * 256;
    const unsigned short* A  = Qt + ((size_t)b * N_ + j0) * C_;
    const unsigned short* Bm = Kt + ((size_t)b * N_ + kc0) * C_;

    int t = threadIdx.x;
    int w = t >> 6, lane = t & 63, l15 = lane & 15, quad = lane >> 4;
    int wm = w >> 2, wn = w & 3;
    int srow = lane >> 2;                              // row within 16-row seg
    int sch  = (((lane & 3) ^ ((lane >> 3) & 3))) * 8; // swizzled source chunk (elems)
    int slotq = (quad ^ ((l15 >> 1) & 3)) * 8;         // frag-read slot (elems)

    f32x4 acc[8][4] = {};

    const int NT = 16;                       // K=512 / BK=32
    // prologue: stage tiles 0..2 into bufs 0..2 (12 loads/thread)
#pragma unroll
    for (int tt = 0; tt < 3; ++tt) {
        unsigned short* dst = sm + (tt << 14);
        size_t k0 = (size_t)tt << 5;
#pragma unroll
        for (int i = 0; i < 2; ++i) {
            int seg = w * 2 + i;
            size_t row = (size_t)seg * 16 + srow;
            async16(&A [row * C_ + k0 + sch], dst + seg * 512);
            async16(&Bm[row * C_ + k0 + sch], dst + 8192 + seg * 512);
        }
    }
    __builtin_amdgcn_s_waitcnt(0x3F78);      // vmcnt(8): tile 0 landed
    __builtin_amdgcn_s_barrier();

    for (int tt = 0; tt < NT; ++tt) {
        const unsigned short* bp = sm + ((tt & 3) << 14);
        unsigned short* stg = sm + (((tt + 3) & 3) << 14);
        const bool dostage = (tt + 3 < NT);
        size_t k0n = (size_t)(tt + 3) << 5;
        // frag reads (wave-private; compiler pipelines via lgkmcnt)
        bf16x8 bfr[4], af[4], af2[4];
#pragma unroll
        for (int ni = 0; ni < 4; ++ni)
            bfr[ni] = *(const bf16x8*)&bp[8192 + (wn * 64 + ni * 16 + l15) * 32 + slotq];
#pragma unroll
        for (int mi = 0; mi < 4; ++mi)
            af[mi] = *(const bf16x8*)&bp[(wm * 128 + mi * 16 + l15) * 32 + slotq];
        if (dostage) {                       // stage A half of tile tt+3
#pragma unroll
            for (int i = 0; i < 2; ++i) {
                int seg = w * 2 + i;
                size_t row = (size_t)seg * 16 + srow;
                async16(&A[row * C_ + k0n + sch], stg + seg * 512);
            }
        }
        __builtin_amdgcn_s_setprio(1);
#pragma unroll
        for (int mi = 0; mi < 4; ++mi)
#pragma unroll
            for (int ni = 0; ni < 4; ++ni)
                acc[mi][ni] = MFMA16(af[mi], bfr[ni], acc[mi][ni]);
        __builtin_amdgcn_s_setprio(0);
#pragma unroll
        for (int mi = 0; mi < 4; ++mi)
            af2[mi] = *(const bf16x8*)&bp[(wm * 128 + (mi + 4) * 16 + l15) * 32 + slotq];
        if (dostage) {                       // stage B half of tile tt+3
#pragma unroll
            for (int i = 0; i < 2; ++i) {
                int seg = w * 2 + i;
                size_t row = (size_t)seg * 16 + srow;
                async16(&Bm[row * C_ + k0n + sch], stg + 8192 + seg * 512);
            }
        }
        __builtin_amdgcn_s_setprio(1);
#pragma unroll
        for (int mi = 0; mi < 4; ++mi)
#pragma unroll
            for (int ni = 0; ni < 4; ++ni)
                acc[4 + mi][ni] = MFMA16(af2[mi], bfr[ni], acc[4 + mi][ni]);
        __builtin_amdgcn_s_setprio(0);
        // ---- tile boundary: counted wait for tile tt+1's staging
        if (tt + 1 < NT) {
            if (tt < NT - 3)       __builtin_amdgcn_s_waitcnt(0x3F78); // vmcnt(8)
            else if (tt == NT - 3) __builtin_amdgcn_s_waitcnt(0x3F74); // vmcnt(4)
            else                   __builtin_amdgcn_s_waitcnt(0x3F70); // vmcnt(0)
            __builtin_amdgcn_s_barrier();
        }
    }

    // ---- epilogue: exp + P store + per-wave rowsum partials
#pragma unroll
    for (int mi = 0; mi < 8; ++mi) {
        float rs[4] = {0.f, 0.f, 0.f, 0.f};
#pragma unroll
        for (int ni = 0; ni < 4; ++ni) {
            int ncol = kc0 + wn * 64 + ni * 16 + l15;
#pragma unroll
            for (int r = 0; r < 4; ++r) {
                int mrow = j0 + wm * 128 + mi * 16 + quad * 4 + r;
                float p = exp2f(__builtin_fmaf(acc[mi][ni][r], SC2, -ES2));
                rs[r] += p;
                P[((size_t)b * N_ + mrow) * N_ + ncol] = f2bf(p);
            }
        }
#pragma unroll
        for (int r = 0; r < 4; ++r) {
            float v = rs[r];
            v += __shfl_xor(v, 1);
            v += __shfl_xor(v, 2);
            v += __shfl_xor(v, 4);
            v += __shfl_xor(v, 8);
            if (l15 == 0)
                psum[(size_t)(wn * 16 + ky) * 16384 +
                     (size_t)b * N_ + j0 + wm * 128 + mi * 16 + quad * 4 + r] = v;
        }
    }
}

// ------------- GEMM2 (R10): O = (P V) / l -> AObf[b][n][c] bf16 -------------
// 256x128 tile, 8 waves (4M x 2N), BK=32, ring-4 LDS, counted vmcnt(6),
// ONE barrier per K-tile (mid barrier removed), K=4096 (128 tiles, no tail).
// XCD swizzle: the 4 ct-blocks sharing a 2 MB P-tile land on one XCD.
__global__ __launch_bounds__(512, 2) void gemm_pv(const unsigned short* __restrict__ P,
                                                  const unsigned short* __restrict__ Vg,
                                                  const float* __restrict__ psum,
                                                  unsigned short* __restrict__ ao) {
    extern __shared__ unsigned short sm[];   // 4 bufs x (A 8192 | B 4096) ushorts
    __shared__ float linv[256];
    int lin = blockIdx.x;                    // 0..255
    int xcd = lin & 7;
    int i4  = lin >> 3;                      // 0..31
    int ct  = i4 & 3;
    int grp = xcd + 8 * (i4 >> 2);           // 0..63
    int b = grp & 3, qtile = grp >> 2;
    int j0 = qtile * 256, co0 = ct * 128;
    int t = threadIdx.x;
    int w = t >> 6, lane = t & 63, l15 = lane & 15, quad = lane >> 4;
    int wm = w >> 1, wn = w & 1;
    int srow = lane >> 2;
    int sch  = ((lane & 3) ^ ((lane >> 3) & 3)) * 8;
    int slotq = (quad ^ ((l15 >> 1) & 3)) * 8;
    const unsigned short* A  = P  + ((size_t)b * N_ + j0) * N_;
    const unsigned short* Bm = Vg + ((size_t)b * C_ + co0) * N_;
    f32x4 acc[4][4] = {};
    const int NT = 128;                      // K = 4096 / 32
    // prologue: tiles 0..2 -> bufs 0..2 (9 loads/thread)
#pragma unroll
    for (int tt = 0; tt < 3; ++tt) {
        unsigned short* dst = sm + tt * 12288;
        size_t k0 = (size_t)tt << 5;
#pragma unroll
        for (int i = 0; i < 2; ++i) {
            int seg = w * 2 + i;
            size_t row = (size_t)seg * 16 + srow;
            async16(&A[row * N_ + k0 + sch], dst + seg * 512);
        }
        {
            size_t row = (size_t)w * 16 + srow;
            async16(&Bm[row * N_ + k0 + sch], dst + 8192 + w * 512);
        }
    }
    // linv (psum reduction) overlaps the prologue loads
    if (t < 256) {
        size_t q = (size_t)b * N_ + j0 + t;
        float s = 0.f;
#pragma unroll
        for (int i = 0; i < 64; ++i) s += psum[(size_t)i * 16384 + q];
        linv[t] = 1.f / s;
    }
    __builtin_amdgcn_s_waitcnt(0x3F76);      // vmcnt(6): tile 0 landed
    __builtin_amdgcn_s_barrier();
    for (int tt = 0; tt < NT; ++tt) {
        const unsigned short* bp = sm + (tt & 3) * 12288;
        bf16x8 af[4], bfr[4];
#pragma unroll
        for (int mi = 0; mi < 4; ++mi)
            af[mi] = *(const bf16x8*)&bp[(wm * 64 + mi * 16 + l15) * 32 + slotq];
#pragma unroll
        for (int ni = 0; ni < 4; ++ni)
            bfr[ni] = *(const bf16x8*)&bp[8192 + (wn * 64 + ni * 16 + l15) * 32 + slotq];
        if (tt + 3 < NT) {
            unsigned short* stg = sm + ((tt + 3) & 3) * 12288;
            size_t k0n = (size_t)(tt + 3) << 5;
#pragma unroll
            for (int i = 0; i < 2; ++i) {
                int seg = w * 2 + i;
                size_t row = (size_t)seg * 16 + srow;
                async16(&A[row * N_ + k0n + sch], stg + seg * 512);
            }
            {
                size_t row = (size_t)w * 16 + srow;
                async16(&Bm[row * N_ + k0n + sch], stg + 8192 + w * 512);
            }
        }
        __builtin_amdgcn_s_setprio(1);
#pragma unroll
        for (int mi = 0; mi < 4; ++mi)
#pragma unroll
            for (int ni = 0; ni < 4; ++ni)
                acc[mi][ni] = MFMA16(af[mi], bfr[ni], acc[mi][ni]);
        __builtin_amdgcn_s_setprio(0);
        if (tt + 1 < NT) {
            if (tt + 3 < NT)      __builtin_amdgcn_s_waitcnt(0x3F76); // vmcnt(6)
            else if (tt + 2 < NT) __builtin_amdgcn_s_waitcnt(0x3F73); // vmcnt(3)
            else                  __builtin_amdgcn_s_waitcnt(0x3F70); // vmcnt(0)
            __builtin_amdgcn_s_barrier();
        }
    }
    // epilogue: scale by 1/l and store
#pragma unroll
    for (int mi = 0; mi < 4; ++mi)
#pragma unroll
        for (int ni = 0; ni < 4; ++ni)
#pragma unroll
            for (int r = 0; r < 4; ++r) {
                int mrow = wm * 64 + mi * 16 + quad * 4 + r;
                int ncol = wn * 64 + ni * 16 + l15;
                ao[((size_t)b * N_ + j0 + mrow) * C_ + co0 + ncol] =
                    f2bf(acc[mi][ni][r] * linv[mrow]);
            }
}

// ------------- final projection + residual: grid (32, 4, 4) -----------------
__global__ __launch_bounds__(256) void gemm_resid(const unsigned short* __restrict__ AObf,
                                                  const unsigned short* __restrict__ Wo,
                                                  const float* __restrict__ bo,
                                                  const float* __restrict__ xres,
                                                  float* __restrict__ out) {
    int b = blockIdx.z, j0 = blockIdx.x * 128, co0 = blockIdx.y * 128;
    const unsigned short* A = AObf + ((size_t)b * N_ + j0) * C_;
    const unsigned short* B = Wo + (size_t)co0 * C_;
    gemm_core(A, B, C_, C_, C_,
        [&](f32x4 (&acc)[4][4], int wm, int wn, int l15, int quad) {
#pragma unroll
        for (int mi = 0; mi < 4; ++mi)
#pragma unroll
            for (int ni = 0; ni < 4; ++ni) {
                int ncol = wn * 64 + ni * 16 + l15;
                int jb = j0 + wm * 64 + mi * 16 + quad * 4;
                size_t o = ((size_t)b * C_ + co0 + ncol) * N_ + jb;
                float bb = bo[co0 + ncol];
                float4 xr = *(const float4*)&xres[o];
                float4 ov;
                ov.x = acc[mi][ni][0] + bb + xr.x;
                ov.y = acc[mi][ni][1] + bb + xr.y;
                ov.z = acc[mi][ni][2] + bb + xr.z;
                ov.w = acc[mi][ni][3] + bb + xr.w;
                *(float4*)&out[o] = ov;
            }
    });
}

// ------------- FALLBACK: R4 flash attention (if ws too small) ---------------
__global__ __launch_bounds__(256, 1) void flash_attn(const unsigned short* __restrict__ Qt,
                                                     const unsigned short* __restrict__ Kt,
                                                     const unsigned short* __restrict__ Vg,
                                                     unsigned short* __restrict__ part,
                                                     float* __restrict__ lbuf,
                                                     int nsplit) {
    extern __shared__ unsigned short smem[];
    unsigned short* Kl = smem;
    unsigned short* Vl = smem + 32768;
    unsigned short* Pl = smem + 65536;

    int flat = blockIdx.x;
    int qblk, b, s;
    if (nsplit == 2) { s = flat & 1; b = (flat >> 1) & 3; qblk = flat >> 3; }
    else             { s = 0;        b = flat & 3;        qblk = flat >> 2; }
    int q0 = qblk * 128;
    int t = threadIdx.x, w = t >> 6, lane = t & 63, l15 = lane & 15, quad = lane >> 4;
    int klen = N_ / nsplit, kbeg = s * klen, nkt = klen / 32;
    int xr = l15 & 7;

    const unsigned short* Kbase = Kt + (size_t)b * N_ * C_;
    const unsigned short* Vbase = Vg + (size_t)b * C_ * N_;

    bf16x8 qa[2][16];
#pragma unroll
    for (int u = 0; u < 2; ++u) {
        const unsigned short* qb =
            Qt + ((size_t)b * N_ + q0 + w * 32 + u * 16 + l15) * C_ + quad * 8;
#pragma unroll
        for (int ck = 0; ck < 16; ++ck) qa[u][ck] = *(const bf16x8*)(qb + ck * 32);
    }

    f32x4 o[2][32] = {};
    float lrow[2][4] = {};

    {
        int k0 = kbeg;
#pragma unroll
        for (int i = 0; i < 8; ++i) {
            int r = w * 8 + i;
            async16(Kbase + (size_t)(k0 + r) * C_ + ((lane ^ (r & 7)) * 8), Kl + r * 512);
        }
#pragma unroll
        for (int i = 0; i < 8; ++i) {
            int idx = w * 8 + i, kc = idx >> 3, cb = idx & 7;
            async16(Vbase + (size_t)(cb * 64 + lane) * N_ + k0 + kc * 8,
                    Vl + (kc * 512 + cb * 64) * 8);
        }
    }

    for (int kt = 0; kt < nkt; ++kt) {
        int cur = kt & 1, nxt = cur ^ 1;
        __builtin_amdgcn_s_waitcnt(0x3F70);
        __syncthreads();
        if (kt + 1 < nkt) {
            int k0 = kbeg + (kt + 1) * 32;
#pragma unroll
            for (int i = 0; i < 8; ++i) {
                int r = w * 8 + i;
                async16(Kbase + (size_t)(k0 + r) * C_ + ((lane ^ (r & 7)) * 8),
                        Kl + nxt * 16384 + r * 512);
            }
#pragma unroll
            for (int i = 0; i < 8; ++i) {
                int idx = w * 8 + i, kc = idx >> 3, cb = idx & 7;
                async16(Vbase + (size_t)(cb * 64 + lane) * N_ + k0 + kc * 8,
                        Vl + nxt * 16384 + (kc * 512 + cb * 64) * 8);
            }
        }
        const unsigned short* Kc = Kl + cur * 16384;
        f32x4 s00 = {}, s01 = {}, s10 = {}, s11 = {};
#pragma unroll
        for (int ck = 0; ck < 16; ++ck) {
            int slot = (ck * 4 + quad) ^ xr;
            bf16x8 b0 = *(const bf16x8*)&Kc[l15 * 512 + slot * 8];
            bf16x8 b1 = *(const bf16x8*)&Kc[(16 + l15) * 512 + slot * 8];
            s00 = MFMA16(qa[0][ck], b0, s00);
            s10 = MFMA16(qa[1][ck], b0, s10);
            s01 = MFMA16(qa[0][ck], b1, s01);
            s11 = MFMA16(qa[1][ck], b1, s11);
        }
        unsigned short* pb = &Pl[w * 1152];
#pragma unroll
        for (int r = 0; r < 4; ++r) {
            float p00 = __expf(s00[r] * SCALE - ESHIFT);
            float p01 = __expf(s01[r] * SCALE - ESHIFT);
            float p10 = __expf(s10[r] * SCALE - ESHIFT);
            float p11 = __expf(s11[r] * SCALE - ESHIFT);
            lrow[0][r] += p00 + p01;
            lrow[1][r] += p10 + p11;
            int row0 = (quad * 4 + r) * 36;
            int row1 = (16 + quad * 4 + r) * 36;
            pb[row0 + l15]      = f2bf(p00);
            pb[row0 + 16 + l15] = f2bf(p01);
            pb[row1 + l15]      = f2bf(p10);
            pb[row1 + 16 + l15] = f2bf(p11);
        }
        __builtin_amdgcn_s_waitcnt(0xC07F);
        bf16x8 pa0 = *(const bf16x8*)&Pl[w * 1152 + l15 * 36 + quad * 8];
        bf16x8 pa1 = *(const bf16x8*)&Pl[w * 1152 + (16 + l15) * 36 + quad * 8];
        const unsigned short* Vc = Vl + cur * 16384;
#pragma unroll
        for (int cf = 0; cf < 32; ++cf) {
            bf16x8 vb = *(const bf16x8*)&Vc[(quad * 512 + cf * 16 + l15) * 8];
            o[0][cf] = MFMA16(pa0, vb, o[0][cf]);
            o[1][cf] = MFMA16(pa1, vb, o[1][cf]);
        }
    }
#pragma unroll
    for (int u = 0; u < 2; ++u)
#pragma unroll
        for (int r = 0; r < 4; ++r) {
            float l = lrow[u][r];
            l += __shfl_xor(l, 1);
            l += __shfl_xor(l, 2);
            l += __shfl_xor(l, 4);
            l += __shfl_xor(l, 8);
            lrow[u][r] = l;
        }
    size_t pbase = (size_t)(s * B_ + b) * N_;
#pragma unroll
    for (int u = 0; u < 2; ++u)
#pragma unroll
        for (int cf = 0; cf < 32; ++cf)
#pragma unroll
            for (int r = 0; r < 4; ++r) {
                int q = q0 + w * 32 + u * 16 + quad * 4 + r;
                part[(pbase + q) * C_ + cf * 16 + l15] = f2bf(o[u][cf][r]);
            }
    if (l15 == 0) {
#pragma unroll
        for (int u = 0; u < 2; ++u)
#pragma unroll
            for (int r = 0; r < 4; ++r) {
                int q = q0 + w * 32 + u * 16 + quad * 4 + r;
                lbuf[pbase + q] = lrow[u][r];
            }
    }
}

__global__ __launch_bounds__(256) void attn_combine(const unsigned short* __restrict__ part,
                                                    const float* __restrict__ lbuf,
                                                    unsigned short* __restrict__ ao,
                                                    int nsplit) {
    size_t idx = (size_t)blockIdx.x * 256 + threadIdx.x;
    int cu = (int)(idx & 63);
    size_t row = idx >> 6;
    float l = lbuf[row];
    union { uint4 v; unsigned short u[8]; } p1, p2, outv;
    p1.v = *(const uint4*)&part[row * C_ + cu * 8];
    if (nsplit == 2) {
        l += lbuf[(size_t)B_ * N_ + row];
        p2.v = *(const uint4*)&part[((size_t)B_ * N_ + row) * C_ + cu * 8];
    } else {
        p2.v = make_uint4(0, 0, 0, 0);
    }
    float inv = 1.f / l;
#pragma unroll
    for (int j = 0; j < 8; ++j)
        outv.u[j] = f2bf((bf2f(p1.u[j]) + bf2f(p2.u[j])) * inv);
    *(uint4*)&ao[row * C_ + cu * 8] = outv.v;
}

// ---------------------------------------------------------------------------
extern "C" void kernel_launch(void* const* d_in, const int* in_sizes, int n_in,
                              void* d_out, int out_size, void* d_ws, size_t ws_size,
                              hipStream_t stream) {
    const float* x   = (const float*)d_in[0];
    const float* gam = (const float*)d_in[1];
    const float* bet = (const float*)d_in[2];
    const float* wq  = (const float*)d_in[3];
    const float* bq  = (const float*)d_in[4];
    const float* wk  = (const float*)d_in[5];
    const float* bk  = (const float*)d_in[6];
    const float* wv  = (const float*)d_in[7];
    const float* bv  = (const float*)d_in[8];
    const float* wo  = (const float*)d_in[9];
    const float* bo  = (const float*)d_in[10];
    float* out = (float*)d_out;

    char* ws = (char*)d_ws;
    const size_t SZH = (size_t)B_ * N_ * C_ * 2;          // 16 MiB bf16 tensor
    const size_t OFF_HT = 4096;
    const size_t OFF_QT = OFF_HT + SZH;
    const size_t OFF_KT = OFF_QT + SZH;
    const size_t OFF_VG = OFF_KT + SZH;
    const size_t OFF_WB = OFF_VG + SZH;
    const size_t OFF_X  = OFF_WB + 2097152;               // 69,210,112
    float*          part0 = (float*)ws;                   // gn partial sums
    unsigned short* Ht    = (unsigned short*)(ws + OFF_HT);
    unsigned short* Qt    = (unsigned short*)(ws + OFF_QT);
    unsigned short* Kt    = (unsigned short*)(ws + OFF_KT);
    unsigned short* Vg    = (unsigned short*)(ws + OFF_VG);
    unsigned short* Wb    = (unsigned short*)(ws + OFF_WB);
    unsigned short* AObf  = Ht;  // Ht dead after projections

    // Path A: materialized-P two-GEMM attention.
    const size_t SZPSUM = 64ull * 16384 * 4;              // 4 MiB
    const size_t SZP    = (size_t)B_ * N_ * N_ * 2;       // 128 MiB
    float*          psum = (float*)(ws + OFF_X);
    unsigned short* P    = (unsigned short*)(ws + OFF_X + SZPSUM);
    size_t needA = OFF_X + SZPSUM + SZP;

    // Path B (fallback): R4 flash.
    float*          lbuf = (float*)(ws + OFF_X);
    unsigned short* partb = (unsigned short*)(ws + OFF_X + 262144);
    size_t needB2 = OFF_X + 262144 + 2 * SZH;

    gn_partial<<<512, 256, 0, stream>>>(x, part0);
    gn_apply<<<dim3(64, 8, B_), 256, 0, stream>>>(x, gam, bet, part0, Ht);
    wconv<<<4096, 256, 0, stream>>>(wq, wk, wv, wo, Wb);
    gemm_qkv<<<dim3(32, 12, B_), 256, 0, stream>>>(Ht, Wb, bq, bk, bv, Qt, Kt, Vg);

    if (ws_size >= needA) {
        const int QK_LDS = 131072;   // 4 ring bufs x 32 KiB
        (void)hipFuncSetAttribute((const void*)gemm_qk_exp,
                                  hipFuncAttributeMaxDynamicSharedMemorySize, QK_LDS);
        gemm_qk_exp<<<dim3(16, 16, B_), 512, QK_LDS, stream>>>(Qt, Kt, P, psum);
        const int PV_LDS = 98304;    // 4 ring bufs x 24 KiB
        (void)hipFuncSetAttribute((const void*)gemm_pv,
                                  hipFuncAttributeMaxDynamicSharedMemorySize, PV_LDS);
        gemm_pv<<<256, 512, PV_LDS, stream>>>(P, Vg, psum, AObf);
    } else {
        int nsplit = (ws_size >= needB2) ? 2 : 1;
        const int FLASH_LDS = 140288;
        (void)hipFuncSetAttribute((const void*)flash_attn,
                                  hipFuncAttributeMaxDynamicSharedMemorySize, FLASH_LDS);
        flash_attn<<<dim3(32 * B_ * nsplit), 256, FLASH_LDS, stream>>>(Qt, Kt, Vg, partb, lbuf, nsplit);
        attn_combine<<<4096, 256, 0, stream>>>(partb, lbuf, AObf, nsplit);
    }
    gemm_resid<<<dim3(32, 4, B_), 256, 0, stream>>>(AObf, Wb + 786432, bo, x, out);
}

// Round 4
// 320.683 us; speedup vs baseline: 1.1546x; 1.0146x over previous
//
#include <hip/hip_runtime.h>

// ---------------------------------------------------------------------------
// AttnBlock: GroupNorm -> q,k,v 1x1 conv -> softmax(QK^T/sqrt(c)) V -> out
// conv -> residual.  b=4, c=512, h=w=64 (n=4096), 32 groups.
// R11: 2-tile barrier windows.  qk/pv: ring-4 LDS, stage-depth-2 (stage X
//      during X-2), s_barrier only every 2 K-tiles (ring-4 safe: stage
//      targets {tt+2,tt+3}&3 never hit readers {tt,tt+1}&3).  Mid-window
//      sync is a wave-local counted vmcnt + sched_barrier(0) fence -- waves
//      drift, LDS-port bursts decorrelate from MFMA bursts, compiler gets
//      cross-tile read/MFMA overlap.  Counted vmcnt steady-state (4 for qk,
//      3 for pv), drains only at the tail.
// ---------------------------------------------------------------------------

typedef __attribute__((ext_vector_type(8))) short bf16x8;   // 8 bf16 (4 VGPR)
typedef __attribute__((ext_vector_type(4))) float f32x4;    // MFMA acc frag

#define MFMA16(a, b, c) __builtin_amdgcn_mfma_f32_16x16x32_bf16((a), (b), (c), 0, 0, 0)

#define B_   4
#define C_   512
#define N_   4096
#define SCALE 0.044194173824159216f  // 1/sqrt(512)
#define ESHIFT 12.0f                 // uniform exp shift (overflow insurance)
#define SC2   0.06376297465050853f   // SCALE * log2(e)
#define ES2   17.312340490667562f    // ESHIFT * log2(e)

__device__ __forceinline__ unsigned short f2bf(float f) {
    union { float f; unsigned int u; } v; v.f = f;
    unsigned int r = (v.u + 0x7fffu + ((v.u >> 16) & 1u)) >> 16;  // RNE
    return (unsigned short)r;
}
__device__ __forceinline__ float bf2f(unsigned short s) {
    union { unsigned int u; float f; } v; v.u = ((unsigned int)s) << 16;
    return v.f;
}

// async 16B global -> LDS (lane i lands at lds + i*16)
__device__ __forceinline__ void async16(const unsigned short* g, unsigned short* l) {
    __builtin_amdgcn_global_load_lds((const __attribute__((address_space(1))) unsigned int*)g,
                                     (__attribute__((address_space(3))) unsigned int*)l,
                                     16, 0, 0);
}

// ---------------- GroupNorm partial sums: 512 blocks (4 per group) ----------
__global__ __launch_bounds__(256) void gn_partial(const float* __restrict__ x,
                                                  float* __restrict__ part) {
    int blk = blockIdx.x;           // 0..511
    int gid = blk >> 2, qtr = blk & 3;
    const float4* base = (const float4*)(x + (size_t)gid * 65536) + qtr * 4096;
    float s = 0.f, ss = 0.f;
    for (int i = threadIdx.x; i < 4096; i += 256) {
        float4 v = base[i];
        s  += v.x + v.y + v.z + v.w;
        ss += v.x * v.x + v.y * v.y + v.z * v.z + v.w * v.w;
    }
    __shared__ float red[512];
    int t = threadIdx.x;
    red[t] = s; red[256 + t] = ss;
    __syncthreads();
    for (int st = 128; st > 0; st >>= 1) {
        if (t < st) { red[t] += red[t + st]; red[256 + t] += red[256 + t + st]; }
        __syncthreads();
    }
    if (t == 0) { part[blk] = red[0]; part[512 + blk] = red[256]; }
}

// ------------- GroupNorm apply + transpose -> Ht[b][n][c] bf16 --------------
__global__ __launch_bounds__(256) void gn_apply(const float* __restrict__ x,
                                                const float* __restrict__ gamma,
                                                const float* __restrict__ beta,
                                                const float* __restrict__ part,
                                                unsigned short* __restrict__ ht) {
    __shared__ float tile[64][65];
    __shared__ float mrs[4][2];
    int j0 = blockIdx.x * 64, c0 = blockIdx.y * 64, b = blockIdx.z;
    int t = threadIdx.x;
    if (t < 4) {
        int gid = b * 32 + (c0 >> 4) + t;
        float s = 0.f, ss = 0.f;
#pragma unroll
        for (int q = 0; q < 4; ++q) { s += part[gid * 4 + q]; ss += part[512 + gid * 4 + q]; }
        float mean = s * (1.f / 65536.f);
        float var  = ss * (1.f / 65536.f) - mean * mean;
        mrs[t][0] = mean;
        mrs[t][1] = rsqrtf(var + 1e-6f);
    }
    __syncthreads();
#pragma unroll
    for (int i = 0; i < 16; ++i) {
        int lid = i * 256 + t;
        int cl = lid >> 6, jl = lid & 63;
        int c = c0 + cl;
        float v = x[((size_t)b * C_ + c) * N_ + j0 + jl];
        tile[cl][jl] = (v - mrs[cl >> 4][0]) * mrs[cl >> 4][1] * gamma[c] + beta[c];
    }
    __syncthreads();
#pragma unroll
    for (int i = 0; i < 16; ++i) {
        int lid = i * 256 + t;
        int jl = lid >> 6, cl = lid & 63;
        ht[((size_t)b * N_ + j0 + jl) * C_ + c0 + cl] = f2bf(tile[cl][jl]);
    }
}

// ------------- convert the 4 weight matrices to bf16 ------------------------
__global__ __launch_bounds__(256) void wconv(const float* __restrict__ wq,
                                             const float* __restrict__ wk,
                                             const float* __restrict__ wv,
                                             const float* __restrict__ wo,
                                             unsigned short* __restrict__ dst) {
    size_t i = (size_t)blockIdx.x * 256 + threadIdx.x;  // 4*512*512 total
    int m = (int)(i >> 18);
    size_t off = i & 262143;
    const float* src = (m == 0) ? wq : (m == 1) ? wk : (m == 2) ? wv : wo;
    dst[i] = f2bf(src[off]);
}

// ------------- 128x128xK MFMA GEMM core: dbuf + XOR-swizzled LDS ------------
template <typename EPI>
__device__ __forceinline__ void gemm_core(const unsigned short* __restrict__ Abase,
                                          const unsigned short* __restrict__ Bbase,
                                          size_t lda, size_t ldb, int K, EPI epi) {
    __shared__ unsigned short hl[2][128 * 64];
    __shared__ unsigned short wl[2][128 * 64];
    int t = threadIdx.x;
    int wv = t >> 6, lane = t & 63, l15 = lane & 15, quad = lane >> 4;
    int wm = wv & 1, wn = wv >> 1;
    int srow = lane >> 3;                    // row within 8-row seg
    int sch  = ((lane & 7) ^ srow) * 8;      // XOR-swizzled chunk offset
    int xr = l15 & 7;
    f32x4 acc[4][4] = {};
    // prologue: stage tile 0 into buf 0
#pragma unroll
    for (int i = 0; i < 4; ++i) {
        int seg = wv * 4 + i;
        size_t row = seg * 8 + srow;
        async16(&Abase[row * lda + sch], &hl[0][seg * 512]);
        async16(&Bbase[row * ldb + sch], &wl[0][seg * 512]);
    }
    int nk = K >> 6;
    for (int k = 0; k < nk; ++k) {
        int cur = k & 1;
        __builtin_amdgcn_s_waitcnt(0x3F70);  // vmcnt(0)
        __syncthreads();
        if (k + 1 < nk) {                    // prefetch k+1 (post-barrier: buf free)
            int k0 = (k + 1) << 6;
#pragma unroll
            for (int i = 0; i < 4; ++i) {
                int seg = wv * 4 + i;
                size_t row = seg * 8 + srow;
                async16(&Abase[row * lda + k0 + sch], &hl[cur ^ 1][seg * 512]);
                async16(&Bbase[row * ldb + k0 + sch], &wl[cur ^ 1][seg * 512]);
            }
        }
#pragma unroll
        for (int kk = 0; kk < 2; ++kk) {
            int sl = (((kk << 2) + quad) ^ xr) * 8;
            bf16x8 af[4], bfr[4];
#pragma unroll
            for (int mi = 0; mi < 4; ++mi)
                af[mi] = *(const bf16x8*)&hl[cur][(wm * 64 + mi * 16 + l15) * 64 + sl];
#pragma unroll
            for (int ni = 0; ni < 4; ++ni)
                bfr[ni] = *(const bf16x8*)&wl[cur][(wn * 64 + ni * 16 + l15) * 64 + sl];
#pragma unroll
            for (int mi = 0; mi < 4; ++mi)
#pragma unroll
                for (int ni = 0; ni < 4; ++ni)
                    acc[mi][ni] = MFMA16(af[mi], bfr[ni], acc[mi][ni]);
        }
    }
    epi(acc, wm, wn, l15, quad);
}

// ------------- fused QKV projection: grid (32, 12, 4) -----------------------
__global__ __launch_bounds__(256) void gemm_qkv(const unsigned short* __restrict__ Ht,
                                                const unsigned short* __restrict__ Wb,
                                                const float* __restrict__ bq,
                                                const float* __restrict__ bk,
                                                const float* __restrict__ bv,
                                                unsigned short* __restrict__ Qt,
                                                unsigned short* __restrict__ Kt,
                                                unsigned short* __restrict__ Vg) {
    int b = blockIdx.z, j0 = blockIdx.x * 128;
    int ct = blockIdx.y;                 // 0..11
    int slab = ct >> 2, co0 = (ct & 3) * 128;
    const unsigned short* A = Ht + ((size_t)b * N_ + j0) * C_;
    const unsigned short* B = Wb + (size_t)slab * C_ * C_ + (size_t)co0 * C_;
    const float* bias = (slab == 0) ? bq : (slab == 1) ? bk : bv;
    unsigned short* outqk = (slab == 0) ? Qt : Kt;
    gemm_core(A, B, C_, C_, C_,
        [&](f32x4 (&acc)[4][4], int wm, int wn, int l15, int quad) {
        if (slab < 2) {
#pragma unroll
            for (int mi = 0; mi < 4; ++mi)
#pragma unroll
                for (int ni = 0; ni < 4; ++ni)
#pragma unroll
                    for (int r = 0; r < 4; ++r) {
                        int mrow = wm * 64 + mi * 16 + quad * 4 + r;
                        int ncol = wn * 64 + ni * 16 + l15;
                        outqk[((size_t)b * N_ + j0 + mrow) * C_ + co0 + ncol] =
                            f2bf(acc[mi][ni][r] + bias[co0 + ncol]);
                    }
        } else {
#pragma unroll
            for (int mi = 0; mi < 4; ++mi)
#pragma unroll
                for (int ni = 0; ni < 4; ++ni) {
                    int ncol = wn * 64 + ni * 16 + l15;
                    float bb = bias[co0 + ncol];
                    ushort4 pk;
                    pk.x = f2bf(acc[mi][ni][0] + bb);
                    pk.y = f2bf(acc[mi][ni][1] + bb);
                    pk.z = f2bf(acc[mi][ni][2] + bb);
                    pk.w = f2bf(acc[mi][ni][3] + bb);
                    int jb = j0 + wm * 64 + mi * 16 + quad * 4;
                    *(ushort4*)&Vg[((size_t)b * C_ + co0 + ncol) * N_ + jb] = pk;
                }
        }
    });
}

// ------------- GEMM1 (R11): P = exp(Q K^T * scale - 12), rowsum partials ----
// 256x256 tile, 8 waves (2M x 4N), BK=32, ring-4 LDS, stage-depth-2,
// barrier every 2 tiles; mid-window wave-local vmcnt(4)+sched_barrier.
// XCD rect swizzle for L2-resident panels.
__global__ __launch_bounds__(512, 2) void gemm_qk_exp(const unsigned short* __restrict__ Qt,
                                                      const unsigned short* __restrict__ Kt,
                                                      unsigned short* __restrict__ P,
                                                      float* __restrict__ psum) {
    extern __shared__ unsigned short sm[];   // 4 bufs x (A 8192 | B 8192) ushorts
    // XCD rectangle remap (1024 blocks = 4 rounds of 256; xcd = lin & 7)
    int lin = blockIdx.x + 16 * blockIdx.y + 256 * blockIdx.z;
    int xcd = lin & 7;
    int i4  = lin >> 3;                 // 0..127
    int idx = i4 & 31;                  // position within the XCD's 32 blocks
    int b   = i4 >> 5;                  // round = batch
    int rq  = xcd & 3, rk = xcd >> 2;   // rect id == xcd
    int j0  = (rq * 4 + (idx & 3)) * 256;
    int ky  = rk * 8 + (idx >> 2);
    int kc0 = ky * 256;
    const unsigned short* A  = Qt + ((size_t)b * N_ + j0) * C_;
    const unsigned short* Bm = Kt + ((size_t)b * N_ + kc0) * C_;

    int t = threadIdx.x;
    int w = t >> 6, lane = t & 63, l15 = lane & 15, quad = lane >> 4;
    int wm = w >> 2, wn = w & 3;
    int srow = lane >> 2;                              // row within 16-row seg
    int sch  = (((lane & 3) ^ ((lane >> 3) & 3))) * 8; // swizzled source chunk (elems)
    int slotq = (quad ^ ((l15 >> 1) & 3)) * 8;         // frag-read slot (elems)

    f32x4 acc[8][4] = {};

    const int NT = 16;                       // K=512 / BK=32
    // prologue: stage tiles 0,1 into bufs 0,1 (8 loads/thread)
#pragma unroll
    for (int tt = 0; tt < 2; ++tt) {
        unsigned short* dst = sm + (tt << 14);
        size_t k0 = (size_t)tt << 5;
#pragma unroll
        for (int i = 0; i < 2; ++i) {
            int seg = w * 2 + i;
            size_t row = (size_t)seg * 16 + srow;
            async16(&A [row * C_ + k0 + sch], dst + seg * 512);
            async16(&Bm[row * C_ + k0 + sch], dst + 8192 + seg * 512);
        }
    }
    __builtin_amdgcn_s_waitcnt(0x3F74);      // vmcnt(4): tile 0 landed, 1 in flight
    __builtin_amdgcn_s_barrier();

    for (int tt = 0; tt < NT; tt += 2) {
#pragma unroll
        for (int s = 0; s < 2; ++s) {
            int tc = tt + s;
            const unsigned short* bp = sm + ((tc & 3) << 14);
            int ts = tc + 2;                 // stage target (depth-2)
            unsigned short* stg = sm + ((ts & 3) << 14);
            const bool dostage = (ts < NT);
            size_t k0n = (size_t)ts << 5;
            bf16x8 bfr[4], af[4], af2[4];
#pragma unroll
            for (int ni = 0; ni < 4; ++ni)
                bfr[ni] = *(const bf16x8*)&bp[8192 + (wn * 64 + ni * 16 + l15) * 32 + slotq];
#pragma unroll
            for (int mi = 0; mi < 4; ++mi)
                af[mi] = *(const bf16x8*)&bp[(wm * 128 + mi * 16 + l15) * 32 + slotq];
            if (dostage) {                   // stage A half of tile ts
#pragma unroll
                for (int i = 0; i < 2; ++i) {
                    int seg = w * 2 + i;
                    size_t row = (size_t)seg * 16 + srow;
                    async16(&A[row * C_ + k0n + sch], stg + seg * 512);
                }
            }
            __builtin_amdgcn_s_setprio(1);
#pragma unroll
            for (int mi = 0; mi < 4; ++mi)
#pragma unroll
                for (int ni = 0; ni < 4; ++ni)
                    acc[mi][ni] = MFMA16(af[mi], bfr[ni], acc[mi][ni]);
            __builtin_amdgcn_s_setprio(0);
#pragma unroll
            for (int mi = 0; mi < 4; ++mi)
                af2[mi] = *(const bf16x8*)&bp[(wm * 128 + (mi + 4) * 16 + l15) * 32 + slotq];
            if (dostage) {                   // stage B half of tile ts
#pragma unroll
                for (int i = 0; i < 2; ++i) {
                    int seg = w * 2 + i;
                    size_t row = (size_t)seg * 16 + srow;
                    async16(&Bm[row * C_ + k0n + sch], stg + 8192 + seg * 512);
                }
            }
            __builtin_amdgcn_s_setprio(1);
#pragma unroll
            for (int mi = 0; mi < 4; ++mi)
#pragma unroll
                for (int ni = 0; ni < 4; ++ni)
                    acc[4 + mi][ni] = MFMA16(af2[mi], bfr[ni], acc[4 + mi][ni]);
            __builtin_amdgcn_s_setprio(0);
            if (s == 0) {                    // mid-window: wave-local counted wait
                if (tt + 2 < NT) __builtin_amdgcn_s_waitcnt(0x3F74); // vmcnt(4)
                else             __builtin_amdgcn_s_waitcnt(0x3F70); // vmcnt(0)
                __builtin_amdgcn_sched_barrier(0);
            }
        }
        if (tt + 2 < NT) {                   // window boundary
            if (tt + 3 < NT) __builtin_amdgcn_s_waitcnt(0x3F74);     // vmcnt(4)
            else             __builtin_amdgcn_s_waitcnt(0x3F70);     // vmcnt(0)
            __builtin_amdgcn_s_barrier();
        }
    }

    // ---- epilogue: exp + P store + per-wave rowsum partials
#pragma unroll
    for (int mi = 0; mi < 8; ++mi) {
        float rs[4] = {0.f, 0.f, 0.f, 0.f};
#pragma unroll
        for (int ni = 0; ni < 4; ++ni) {
            int ncol = kc0 + wn * 64 + ni * 16 + l15;
#pragma unroll
            for (int r = 0; r < 4; ++r) {
                int mrow = j0 + wm * 128 + mi * 16 + quad * 4 + r;
                float p = exp2f(__builtin_fmaf(acc[mi][ni][r], SC2, -ES2));
                rs[r] += p;
                P[((size_t)b * N_ + mrow) * N_ + ncol] = f2bf(p);
            }
        }
#pragma unroll
        for (int r = 0; r < 4; ++r) {
            float v = rs[r];
            v += __shfl_xor(v, 1);
            v += __shfl_xor(v, 2);
            v += __shfl_xor(v, 4);
            v += __shfl_xor(v, 8);
            if (l15 == 0)
                psum[(size_t)(wn * 16 + ky) * 16384 +
                     (size_t)b * N_ + j0 + wm * 128 + mi * 16 + quad * 4 + r] = v;
        }
    }
}

// ------------- GEMM2 (R11): O = (P V) / l -> AObf[b][n][c] bf16 -------------
// 256x128 tile, 8 waves (4M x 2N), BK=32, ring-4 LDS, stage-depth-2,
// barrier every 2 tiles; mid-window wave-local vmcnt(3)+sched_barrier.
// XCD swizzle: the 4 ct-blocks sharing a 2 MB P-tile land on one XCD.
__global__ __launch_bounds__(512, 2) void gemm_pv(const unsigned short* __restrict__ P,
                                                  const unsigned short* __restrict__ Vg,
                                                  const float* __restrict__ psum,
                                                  unsigned short* __restrict__ ao) {
    extern __shared__ unsigned short sm[];   // 4 bufs x (A 8192 | B 4096) ushorts
    __shared__ float linv[256];
    int lin = blockIdx.x;                    // 0..255
    int xcd = lin & 7;
    int i4  = lin >> 3;                      // 0..31
    int ct  = i4 & 3;
    int grp = xcd + 8 * (i4 >> 2);           // 0..63
    int b = grp & 3, qtile = grp >> 2;
    int j0 = qtile * 256, co0 = ct * 128;
    int t = threadIdx.x;
    int w = t >> 6, lane = t & 63, l15 = lane & 15, quad = lane >> 4;
    int wm = w >> 1, wn = w & 1;
    int srow = lane >> 2;
    int sch  = ((lane & 3) ^ ((lane >> 3) & 3)) * 8;
    int slotq = (quad ^ ((l15 >> 1) & 3)) * 8;
    const unsigned short* A  = P  + ((size_t)b * N_ + j0) * N_;
    const unsigned short* Bm = Vg + ((size_t)b * C_ + co0) * N_;
    f32x4 acc[4][4] = {};
    const int NT = 128;                      // K = 4096 / 32
    // prologue: stage tiles 0,1 (6 loads/thread)
#pragma unroll
    for (int tt = 0; tt < 2; ++tt) {
        unsigned short* dst = sm + tt * 12288;
        size_t k0 = (size_t)tt << 5;
#pragma unroll
        for (int i = 0; i < 2; ++i) {
            int seg = w * 2 + i;
            size_t row = (size_t)seg * 16 + srow;
            async16(&A[row * N_ + k0 + sch], dst + seg * 512);
        }
        {
            size_t row = (size_t)w * 16 + srow;
            async16(&Bm[row * N_ + k0 + sch], dst + 8192 + w * 512);
        }
    }
    // linv (psum reduction) overlaps the prologue loads
    if (t < 256) {
        size_t q = (size_t)b * N_ + j0 + t;
        float s = 0.f;
#pragma unroll
        for (int i = 0; i < 64; ++i) s += psum[(size_t)i * 16384 + q];
        linv[t] = 1.f / s;
    }
    __builtin_amdgcn_s_waitcnt(0x3F73);      // vmcnt(3): tile 0 landed, 1 in flight
    __builtin_amdgcn_s_barrier();
    for (int tt = 0; tt < NT; tt += 2) {
#pragma unroll
        for (int s = 0; s < 2; ++s) {
            int tc = tt + s;
            const unsigned short* bp = sm + (tc & 3) * 12288;
            int ts = tc + 2;                 // stage target (depth-2)
            bf16x8 af[4], bfr[4];
#pragma unroll
            for (int mi = 0; mi < 4; ++mi)
                af[mi] = *(const bf16x8*)&bp[(wm * 64 + mi * 16 + l15) * 32 + slotq];
#pragma unroll
            for (int ni = 0; ni < 4; ++ni)
                bfr[ni] = *(const bf16x8*)&bp[8192 + (wn * 64 + ni * 16 + l15) * 32 + slotq];
            if (ts < NT) {
                unsigned short* stg = sm + (ts & 3) * 12288;
                size_t k0n = (size_t)ts << 5;
#pragma unroll
                for (int i = 0; i < 2; ++i) {
                    int seg = w * 2 + i;
                    size_t row = (size_t)seg * 16 + srow;
                    async16(&A[row * N_ + k0n + sch], stg + seg * 512);
                }
                {
                    size_t row = (size_t)w * 16 + srow;
                    async16(&Bm[row * N_ + k0n + sch], stg + 8192 + w * 512);
                }
            }
            __builtin_amdgcn_s_setprio(1);
#pragma unroll
            for (int mi = 0; mi < 4; ++mi)
#pragma unroll
                for (int ni = 0; ni < 4; ++ni)
                    acc[mi][ni] = MFMA16(af[mi], bfr[ni], acc[mi][ni]);
            __builtin_amdgcn_s_setprio(0);
            if (s == 0) {                    // mid-window: wave-local counted wait
                if (tt + 2 < NT) __builtin_amdgcn_s_waitcnt(0x3F73); // vmcnt(3)
                else             __builtin_amdgcn_s_waitcnt(0x3F70); // vmcnt(0)
                __builtin_amdgcn_sched_barrier(0);
            }
        }
        if (tt + 2 < NT) {                   // window boundary
            if (tt + 3 < NT) __builtin_amdgcn_s_waitcnt(0x3F73);     // vmcnt(3)
            else             __builtin_amdgcn_s_waitcnt(0x3F70);     // vmcnt(0)
            __builtin_amdgcn_s_barrier();
        }
    }
    // epilogue: scale by 1/l and store
#pragma unroll
    for (int mi = 0; mi < 4; ++mi)
#pragma unroll
        for (int ni = 0; ni < 4; ++ni)
#pragma unroll
            for (int r = 0; r < 4; ++r) {
                int mrow = wm * 64 + mi * 16 + quad * 4 + r;
                int ncol = wn * 64 + ni * 16 + l15;
                ao[((size_t)b * N_ + j0 + mrow) * C_ + co0 + ncol] =
                    f2bf(acc[mi][ni][r] * linv[mrow]);
            }
}

// ------------- final projection + residual: grid (32, 4, 4) -----------------
__global__ __launch_bounds__(256) void gemm_resid(const unsigned short* __restrict__ AObf,
                                                  const unsigned short* __restrict__ Wo,
                                                  const float* __restrict__ bo,
                                                  const float* __restrict__ xres,
                                                  float* __restrict__ out) {
    int b = blockIdx.z, j0 = blockIdx.x * 128, co0 = blockIdx.y * 128;
    const unsigned short* A = AObf + ((size_t)b * N_ + j0) * C_;
    const unsigned short* B = Wo + (size_t)co0 * C_;
    gemm_core(A, B, C_, C_, C_,
        [&](f32x4 (&acc)[4][4], int wm, int wn, int l15, int quad) {
#pragma unroll
        for (int mi = 0; mi < 4; ++mi)
#pragma unroll
            for (int ni = 0; ni < 4; ++ni) {
                int ncol = wn * 64 + ni * 16 + l15;
                int jb = j0 + wm * 64 + mi * 16 + quad * 4;
                size_t o = ((size_t)b * C_ + co0 + ncol) * N_ + jb;
                float bb = bo[co0 + ncol];
                float4 xr = *(const float4*)&xres[o];
                float4 ov;
                ov.x = acc[mi][ni][0] + bb + xr.x;
                ov.y = acc[mi][ni][1] + bb + xr.y;
                ov.z = acc[mi][ni][2] + bb + xr.z;
                ov.w = acc[mi][ni][3] + bb + xr.w;
                *(float4*)&out[o] = ov;
            }
    });
}

// ------------- FALLBACK: R4 flash attention (if ws too small) ---------------
__global__ __launch_bounds__(256, 1) void flash_attn(const unsigned short* __restrict__ Qt,
                                                     const unsigned short* __restrict__ Kt,
                                                     const unsigned short* __restrict__ Vg,
                                                     unsigned short* __restrict__ part,
                                                     float* __restrict__ lbuf,
                                                     int nsplit) {
    extern __shared__ unsigned short smem[];
    unsigned short* Kl = smem;
    unsigned short* Vl = smem + 32768;
    unsigned short* Pl = smem + 65536;

    int flat = blockIdx.x;
    int qblk, b, s;
    if (nsplit == 2) { s = flat & 1; b = (flat >> 1) & 3; qblk = flat >> 3; }
    else             { s = 0;        b = flat & 3;        qblk = flat >> 2; }
    int q0 = qblk * 128;
    int t = threadIdx.x, w = t >> 6, lane = t & 63, l15 = lane & 15, quad = lane >> 4;
    int klen = N_ / nsplit, kbeg = s * klen, nkt = klen / 32;
    int xr = l15 & 7;

    const unsigned short* Kbase = Kt + (size_t)b * N_ * C_;
    const unsigned short* Vbase = Vg + (size_t)b * C_ * N_;

    bf16x8 qa[2][16];
#pragma unroll
    for (int u = 0; u < 2; ++u) {
        const unsigned short* qb =
            Qt + ((size_t)b * N_ + q0 + w * 32 + u * 16 + l15) * C_ + quad * 8;
#pragma unroll
        for (int ck = 0; ck < 16; ++ck) qa[u][ck] = *(const bf16x8*)(qb + ck * 32);
    }

    f32x4 o[2][32] = {};
    float lrow[2][4] = {};

    {
        int k0 = kbeg;
#pragma unroll
        for (int i = 0; i < 8; ++i) {
            int r = w * 8 + i;
            async16(Kbase + (size_t)(k0 + r) * C_ + ((lane ^ (r & 7)) * 8), Kl + r * 512);
        }
#pragma unroll
        for (int i = 0; i < 8; ++i) {
            int idx = w * 8 + i, kc = idx >> 3, cb = idx & 7;
            async16(Vbase + (size_t)(cb * 64 + lane) * N_ + k0 + kc * 8,
                    Vl + (kc * 512 + cb * 64) * 8);
        }
    }

    for (int kt = 0; kt < nkt; ++kt) {
        int cur = kt & 1, nxt = cur ^ 1;
        __builtin_amdgcn_s_waitcnt(0x3F70);
        __syncthreads();
        if (kt + 1 < nkt) {
            int k0 = kbeg + (kt + 1) * 32;
#pragma unroll
            for (int i = 0; i < 8; ++i) {
                int r = w * 8 + i;
                async16(Kbase + (size_t)(k0 + r) * C_ + ((lane ^ (r & 7)) * 8),
                        Kl + nxt * 16384 + r * 512);
            }
#pragma unroll
            for (int i = 0; i < 8; ++i) {
                int idx = w * 8 + i, kc = idx >> 3, cb = idx & 7;
                async16(Vbase + (size_t)(cb * 64 + lane) * N_ + k0 + kc * 8,
                        Vl + nxt * 16384 + (kc * 512 + cb * 64) * 8);
            }
        }
        const unsigned short* Kc = Kl + cur * 16384;
        f32x4 s00 = {}, s01 = {}, s10 = {}, s11 = {};
#pragma unroll
        for (int ck = 0; ck < 16; ++ck) {
            int slot = (ck * 4 + quad) ^ xr;
            bf16x8 b0 = *(const bf16x8*)&Kc[l15 * 512 + slot * 8];
            bf16x8 b1 = *(const bf16x8*)&Kc[(16 + l15) * 512 + slot * 8];
            s00 = MFMA16(qa[0][ck], b0, s00);
            s10 = MFMA16(qa[1][ck], b0, s10);
            s01 = MFMA16(qa[0][ck], b1, s01);
            s11 = MFMA16(qa[1][ck], b1, s11);
        }
        unsigned short* pb = &Pl[w * 1152];
#pragma unroll
        for (int r = 0; r < 4; ++r) {
            float p00 = __expf(s00[r] * SCALE - ESHIFT);
            float p01 = __expf(s01[r] * SCALE - ESHIFT);
            float p10 = __expf(s10[r] * SCALE - ESHIFT);
            float p11 = __expf(s11[r] * SCALE - ESHIFT);
            lrow[0][r] += p00 + p01;
            lrow[1][r] += p10 + p11;
            int row0 = (quad * 4 + r) * 36;
            int row1 = (16 + quad * 4 + r) * 36;
            pb[row0 + l15]      = f2bf(p00);
            pb[row0 + 16 + l15] = f2bf(p01);
            pb[row1 + l15]      = f2bf(p10);
            pb[row1 + 16 + l15] = f2bf(p11);
        }
        __builtin_amdgcn_s_waitcnt(0xC07F);
        bf16x8 pa0 = *(const bf16x8*)&Pl[w * 1152 + l15 * 36 + quad * 8];
        bf16x8 pa1 = *(const bf16x8*)&Pl[w * 1152 + (16 + l15) * 36 + quad * 8];
        const unsigned short* Vc = Vl + cur * 16384;
#pragma unroll
        for (int cf = 0; cf < 32; ++cf) {
            bf16x8 vb = *(const bf16x8*)&Vc[(quad * 512 + cf * 16 + l15) * 8];
            o[0][cf] = MFMA16(pa0, vb, o[0][cf]);
            o[1][cf] = MFMA16(pa1, vb, o[1][cf]);
        }
    }
#pragma unroll
    for (int u = 0; u < 2; ++u)
#pragma unroll
        for (int r = 0; r < 4; ++r) {
            float l = lrow[u][r];
            l += __shfl_xor(l, 1);
            l += __shfl_xor(l, 2);
            l += __shfl_xor(l, 4);
            l += __shfl_xor(l, 8);
            lrow[u][r] = l;
        }
    size_t pbase = (size_t)(s * B_ + b) * N_;
#pragma unroll
    for (int u = 0; u < 2; ++u)
#pragma unroll
        for (int cf = 0; cf < 32; ++cf)
#pragma unroll
            for (int r = 0; r < 4; ++r) {
                int q = q0 + w * 32 + u * 16 + quad * 4 + r;
                part[(pbase + q) * C_ + cf * 16 + l15] = f2bf(o[u][cf][r]);
            }
    if (l15 == 0) {
#pragma unroll
        for (int u = 0; u < 2; ++u)
#pragma unroll
            for (int r = 0; r < 4; ++r) {
                int q = q0 + w * 32 + u * 16 + quad * 4 + r;
                lbuf[pbase + q] = lrow[u][r];
            }
    }
}

__global__ __launch_bounds__(256) void attn_combine(const unsigned short* __restrict__ part,
                                                    const float* __restrict__ lbuf,
                                                    unsigned short* __restrict__ ao,
                                                    int nsplit) {
    size_t idx = (size_t)blockIdx.x * 256 + threadIdx.x;
    int cu = (int)(idx & 63);
    size_t row = idx >> 6;
    float l = lbuf[row];
    union { uint4 v; unsigned short u[8]; } p1, p2, outv;
    p1.v = *(const uint4*)&part[row * C_ + cu * 8];
    if (nsplit == 2) {
        l += lbuf[(size_t)B_ * N_ + row];
        p2.v = *(const uint4*)&part[((size_t)B_ * N_ + row) * C_ + cu * 8];
    } else {
        p2.v = make_uint4(0, 0, 0, 0);
    }
    float inv = 1.f / l;
#pragma unroll
    for (int j = 0; j < 8; ++j)
        outv.u[j] = f2bf((bf2f(p1.u[j]) + bf2f(p2.u[j])) * inv);
    *(uint4*)&ao[row * C_ + cu * 8] = outv.v;
}

// ---------------------------------------------------------------------------
extern "C" void kernel_launch(void* const* d_in, const int* in_sizes, int n_in,
                              void* d_out, int out_size, void* d_ws, size_t ws_size,
                              hipStream_t stream) {
    const float* x   = (const float*)d_in[0];
    const float* gam = (const float*)d_in[1];
    const float* bet = (const float*)d_in[2];
    const float* wq  = (const float*)d_in[3];
    const float* bq  = (const float*)d_in[4];
    const float* wk  = (const float*)d_in[5];
    const float* bk  = (const float*)d_in[6];
    const float* wv  = (const float*)d_in[7];
    const float* bv  = (const float*)d_in[8];
    const float* wo  = (const float*)d_in[9];
    const float* bo  = (const float*)d_in[10];
    float* out = (float*)d_out;

    char* ws = (char*)d_ws;
    const size_t SZH = (size_t)B_ * N_ * C_ * 2;          // 16 MiB bf16 tensor
    const size_t OFF_HT = 4096;
    const size_t OFF_QT = OFF_HT + SZH;
    const size_t OFF_KT = OFF_QT + SZH;
    const size_t OFF_VG = OFF_KT + SZH;
    const size_t OFF_WB = OFF_VG + SZH;
    const size_t OFF_X  = OFF_WB + 2097152;               // 69,210,112
    float*          part0 = (float*)ws;                   // gn partial sums
    unsigned short* Ht    = (unsigned short*)(ws + OFF_HT);
    unsigned short* Qt    = (unsigned short*)(ws + OFF_QT);
    unsigned short* Kt    = (unsigned short*)(ws + OFF_KT);
    unsigned short* Vg    = (unsigned short*)(ws + OFF_VG);
    unsigned short* Wb    = (unsigned short*)(ws + OFF_WB);
    unsigned short* AObf  = Ht;  // Ht dead after projections

    // Path A: materialized-P two-GEMM attention.
    const size_t SZPSUM = 64ull * 16384 * 4;              // 4 MiB
    const size_t SZP    = (size_t)B_ * N_ * N_ * 2;       // 128 MiB
    float*          psum = (float*)(ws + OFF_X);
    unsigned short* P    = (unsigned short*)(ws + OFF_X + SZPSUM);
    size_t needA = OFF_X + SZPSUM + SZP;

    // Path B (fallback): R4 flash.
    float*          lbuf = (float*)(ws + OFF_X);
    unsigned short* partb = (unsigned short*)(ws + OFF_X + 262144);
    size_t needB2 = OFF_X + 262144 + 2 * SZH;

    gn_partial<<<512, 256, 0, stream>>>(x, part0);
    gn_apply<<<dim3(64, 8, B_), 256, 0, stream>>>(x, gam, bet, part0, Ht);
    wconv<<<4096, 256, 0, stream>>>(wq, wk, wv, wo, Wb);
    gemm_qkv<<<dim3(32, 12, B_), 256, 0, stream>>>(Ht, Wb, bq, bk, bv, Qt, Kt, Vg);

    if (ws_size >= needA) {
        const int QK_LDS = 131072;   // 4 ring bufs x 32 KiB
        (void)hipFuncSetAttribute((const void*)gemm_qk_exp,
                                  hipFuncAttributeMaxDynamicSharedMemorySize, QK_LDS);
        gemm_qk_exp<<<dim3(16, 16, B_), 512, QK_LDS, stream>>>(Qt, Kt, P, psum);
        const int PV_LDS = 98304;    // 4 ring bufs x 24 KiB
        (void)hipFuncSetAttribute((const void*)gemm_pv,
                                  hipFuncAttributeMaxDynamicSharedMemorySize, PV_LDS);
        gemm_pv<<<256, 512, PV_LDS, stream>>>(P, Vg, psum, AObf);
    } else {
        int nsplit = (ws_size >= needB2) ? 2 : 1;
        const int FLASH_LDS = 140288;
        (void)hipFuncSetAttribute((const void*)flash_attn,
                                  hipFuncAttributeMaxDynamicSharedMemorySize, FLASH_LDS);
        flash_attn<<<dim3(32 * B_ * nsplit), 256, FLASH_LDS, stream>>>(Qt, Kt, Vg, partb, lbuf, nsplit);
        attn_combine<<<4096, 256, 0, stream>>>(partb, lbuf, AObf, nsplit);
    }
    gemm_resid<<<dim3(32, 4, B_), 256, 0, stream>>>(AObf, Wb + 786432, bo, x, out);
}

// Round 5
// 320.165 us; speedup vs baseline: 1.1565x; 1.0016x over previous
//
#include <hip/hip_runtime.h>

// ---------------------------------------------------------------------------
// AttnBlock: GroupNorm -> q,k,v 1x1 conv -> softmax(QK^T/sqrt(c)) V -> out
// conv -> residual.  b=4, c=512, h=w=64 (n=4096), 32 groups.
// R12: qk_exp re-geometried for 2-block/CU co-residency: 256x128 tile,
//      wave-tile 64x64 (acc=64 AGPR, total regs <=128 -> 4 waves/SIMD),
//      ring-3 LDS 72 KB, stage-depth-2, counted vmcnt(3), 1 barrier/tile.
//      Epilogue/prologue/vmcnt stalls of one block now hide under the
//      co-resident block's MFMAs (R8-R11 analysis: serial tail ~= 27% of
//      the kernel at 1 block/CU).  psum slab = ky*2+wn (still 64 slabs;
//      pv unchanged).  pv/qkv/resid keep R11 structure.
// ---------------------------------------------------------------------------

typedef __attribute__((ext_vector_type(8))) short bf16x8;   // 8 bf16 (4 VGPR)
typedef __attribute__((ext_vector_type(4))) float f32x4;    // MFMA acc frag

#define MFMA16(a, b, c) __builtin_amdgcn_mfma_f32_16x16x32_bf16((a), (b), (c), 0, 0, 0)

#define B_   4
#define C_   512
#define N_   4096
#define SCALE 0.044194173824159216f  // 1/sqrt(512)
#define ESHIFT 12.0f                 // uniform exp shift (overflow insurance)
#define SC2   0.06376297465050853f   // SCALE * log2(e)
#define ES2   17.312340490667562f    // ESHIFT * log2(e)

__device__ __forceinline__ unsigned short f2bf(float f) {
    union { float f; unsigned int u; } v; v.f = f;
    unsigned int r = (v.u + 0x7fffu + ((v.u >> 16) & 1u)) >> 16;  // RNE
    return (unsigned short)r;
}
__device__ __forceinline__ float bf2f(unsigned short s) {
    union { unsigned int u; float f; } v; v.u = ((unsigned int)s) << 16;
    return v.f;
}

// async 16B global -> LDS (lane i lands at lds + i*16)
__device__ __forceinline__ void async16(const unsigned short* g, unsigned short* l) {
    __builtin_amdgcn_global_load_lds((const __attribute__((address_space(1))) unsigned int*)g,
                                     (__attribute__((address_space(3))) unsigned int*)l,
                                     16, 0, 0);
}

// ---------------- GroupNorm partial sums: 512 blocks (4 per group) ----------
__global__ __launch_bounds__(256) void gn_partial(const float* __restrict__ x,
                                                  float* __restrict__ part) {
    int blk = blockIdx.x;           // 0..511
    int gid = blk >> 2, qtr = blk & 3;
    const float4* base = (const float4*)(x + (size_t)gid * 65536) + qtr * 4096;
    float s = 0.f, ss = 0.f;
    for (int i = threadIdx.x; i < 4096; i += 256) {
        float4 v = base[i];
        s  += v.x + v.y + v.z + v.w;
        ss += v.x * v.x + v.y * v.y + v.z * v.z + v.w * v.w;
    }
    __shared__ float red[512];
    int t = threadIdx.x;
    red[t] = s; red[256 + t] = ss;
    __syncthreads();
    for (int st = 128; st > 0; st >>= 1) {
        if (t < st) { red[t] += red[t + st]; red[256 + t] += red[256 + t + st]; }
        __syncthreads();
    }
    if (t == 0) { part[blk] = red[0]; part[512 + blk] = red[256]; }
}

// ------------- GroupNorm apply + transpose -> Ht[b][n][c] bf16 --------------
__global__ __launch_bounds__(256) void gn_apply(const float* __restrict__ x,
                                                const float* __restrict__ gamma,
                                                const float* __restrict__ beta,
                                                const float* __restrict__ part,
                                                unsigned short* __restrict__ ht) {
    __shared__ float tile[64][65];
    __shared__ float mrs[4][2];
    int j0 = blockIdx.x * 64, c0 = blockIdx.y * 64, b = blockIdx.z;
    int t = threadIdx.x;
    if (t < 4) {
        int gid = b * 32 + (c0 >> 4) + t;
        float s = 0.f, ss = 0.f;
#pragma unroll
        for (int q = 0; q < 4; ++q) { s += part[gid * 4 + q]; ss += part[512 + gid * 4 + q]; }
        float mean = s * (1.f / 65536.f);
        float var  = ss * (1.f / 65536.f) - mean * mean;
        mrs[t][0] = mean;
        mrs[t][1] = rsqrtf(var + 1e-6f);
    }
    __syncthreads();
#pragma unroll
    for (int i = 0; i < 16; ++i) {
        int lid = i * 256 + t;
        int cl = lid >> 6, jl = lid & 63;
        int c = c0 + cl;
        float v = x[((size_t)b * C_ + c) * N_ + j0 + jl];
        tile[cl][jl] = (v - mrs[cl >> 4][0]) * mrs[cl >> 4][1] * gamma[c] + beta[c];
    }
    __syncthreads();
#pragma unroll
    for (int i = 0; i < 16; ++i) {
        int lid = i * 256 + t;
        int jl = lid >> 6, cl = lid & 63;
        ht[((size_t)b * N_ + j0 + jl) * C_ + c0 + cl] = f2bf(tile[cl][jl]);
    }
}

// ------------- convert the 4 weight matrices to bf16 ------------------------
__global__ __launch_bounds__(256) void wconv(const float* __restrict__ wq,
                                             const float* __restrict__ wk,
                                             const float* __restrict__ wv,
                                             const float* __restrict__ wo,
                                             unsigned short* __restrict__ dst) {
    size_t i = (size_t)blockIdx.x * 256 + threadIdx.x;  // 4*512*512 total
    int m = (int)(i >> 18);
    size_t off = i & 262143;
    const float* src = (m == 0) ? wq : (m == 1) ? wk : (m == 2) ? wv : wo;
    dst[i] = f2bf(src[off]);
}

// ------------- 128x128xK MFMA GEMM core: dbuf + XOR-swizzled LDS ------------
template <typename EPI>
__device__ __forceinline__ void gemm_core(const unsigned short* __restrict__ Abase,
                                          const unsigned short* __restrict__ Bbase,
                                          size_t lda, size_t ldb, int K, EPI epi) {
    __shared__ unsigned short hl[2][128 * 64];
    __shared__ unsigned short wl[2][128 * 64];
    int t = threadIdx.x;
    int wv = t >> 6, lane = t & 63, l15 = lane & 15, quad = lane >> 4;
    int wm = wv & 1, wn = wv >> 1;
    int srow = lane >> 3;                    // row within 8-row seg
    int sch  = ((lane & 7) ^ srow) * 8;      // XOR-swizzled chunk offset
    int xr = l15 & 7;
    f32x4 acc[4][4] = {};
    // prologue: stage tile 0 into buf 0
#pragma unroll
    for (int i = 0; i < 4; ++i) {
        int seg = wv * 4 + i;
        size_t row = seg * 8 + srow;
        async16(&Abase[row * lda + sch], &hl[0][seg * 512]);
        async16(&Bbase[row * ldb + sch], &wl[0][seg * 512]);
    }
    int nk = K >> 6;
    for (int k = 0; k < nk; ++k) {
        int cur = k & 1;
        __builtin_amdgcn_s_waitcnt(0x3F70);  // vmcnt(0)
        __syncthreads();
        if (k + 1 < nk) {                    // prefetch k+1 (post-barrier: buf free)
            int k0 = (k + 1) << 6;
#pragma unroll
            for (int i = 0; i < 4; ++i) {
                int seg = wv * 4 + i;
                size_t row = seg * 8 + srow;
                async16(&Abase[row * lda + k0 + sch], &hl[cur ^ 1][seg * 512]);
                async16(&Bbase[row * ldb + k0 + sch], &wl[cur ^ 1][seg * 512]);
            }
        }
#pragma unroll
        for (int kk = 0; kk < 2; ++kk) {
            int sl = (((kk << 2) + quad) ^ xr) * 8;
            bf16x8 af[4], bfr[4];
#pragma unroll
            for (int mi = 0; mi < 4; ++mi)
                af[mi] = *(const bf16x8*)&hl[cur][(wm * 64 + mi * 16 + l15) * 64 + sl];
#pragma unroll
            for (int ni = 0; ni < 4; ++ni)
                bfr[ni] = *(const bf16x8*)&wl[cur][(wn * 64 + ni * 16 + l15) * 64 + sl];
#pragma unroll
            for (int mi = 0; mi < 4; ++mi)
#pragma unroll
                for (int ni = 0; ni < 4; ++ni)
                    acc[mi][ni] = MFMA16(af[mi], bfr[ni], acc[mi][ni]);
        }
    }
    epi(acc, wm, wn, l15, quad);
}

// ------------- fused QKV projection: grid (32, 12, 4) -----------------------
__global__ __launch_bounds__(256) void gemm_qkv(const unsigned short* __restrict__ Ht,
                                                const unsigned short* __restrict__ Wb,
                                                const float* __restrict__ bq,
                                                const float* __restrict__ bk,
                                                const float* __restrict__ bv,
                                                unsigned short* __restrict__ Qt,
                                                unsigned short* __restrict__ Kt,
                                                unsigned short* __restrict__ Vg) {
    int b = blockIdx.z, j0 = blockIdx.x * 128;
    int ct = blockIdx.y;                 // 0..11
    int slab = ct >> 2, co0 = (ct & 3) * 128;
    const unsigned short* A = Ht + ((size_t)b * N_ + j0) * C_;
    const unsigned short* B = Wb + (size_t)slab * C_ * C_ + (size_t)co0 * C_;
    const float* bias = (slab == 0) ? bq : (slab == 1) ? bk : bv;
    unsigned short* outqk = (slab == 0) ? Qt : Kt;
    gemm_core(A, B, C_, C_, C_,
        [&](f32x4 (&acc)[4][4], int wm, int wn, int l15, int quad) {
        if (slab < 2) {
#pragma unroll
            for (int mi = 0; mi < 4; ++mi)
#pragma unroll
                for (int ni = 0; ni < 4; ++ni)
#pragma unroll
                    for (int r = 0; r < 4; ++r) {
                        int mrow = wm * 64 + mi * 16 + quad * 4 + r;
                        int ncol = wn * 64 + ni * 16 + l15;
                        outqk[((size_t)b * N_ + j0 + mrow) * C_ + co0 + ncol] =
                            f2bf(acc[mi][ni][r] + bias[co0 + ncol]);
                    }
        } else {
#pragma unroll
            for (int mi = 0; mi < 4; ++mi)
#pragma unroll
                for (int ni = 0; ni < 4; ++ni) {
                    int ncol = wn * 64 + ni * 16 + l15;
                    float bb = bias[co0 + ncol];
                    ushort4 pk;
                    pk.x = f2bf(acc[mi][ni][0] + bb);
                    pk.y = f2bf(acc[mi][ni][1] + bb);
                    pk.z = f2bf(acc[mi][ni][2] + bb);
                    pk.w = f2bf(acc[mi][ni][3] + bb);
                    int jb = j0 + wm * 64 + mi * 16 + quad * 4;
                    *(ushort4*)&Vg[((size_t)b * C_ + co0 + ncol) * N_ + jb] = pk;
                }
        }
    });
}

// ------------- GEMM1 (R12): P = exp(Q K^T * scale - 12), rowsum partials ----
// 256x128 tile, 8 waves (4M x 2N, wave-tile 64x64, acc=64 regs), BK=32,
// ring-3 LDS (72 KB), stage-depth-2, counted vmcnt(3), 1 barrier/tile.
// __launch_bounds__(512,4): 4 waves/SIMD -> 2 blocks/CU co-residency so
// epilogue/prologue/boundary stalls of one block hide under the other.
// XCD rects of 2M x 8N tiles (A 512KB + B 1MB < 4MB L2/XCD).
// psum slab = ky*2 + wn (64 slabs x 16384, pv reduction unchanged).
__global__ __launch_bounds__(512, 4) void gemm_qk_exp(const unsigned short* __restrict__ Qt,
                                                      const unsigned short* __restrict__ Kt,
                                                      unsigned short* __restrict__ P,
                                                      float* __restrict__ psum) {
    extern __shared__ unsigned short sm[];   // 3 bufs x 12288 ushorts (24 KB)
    int lin = blockIdx.x;                    // 0..2047
    int xcd = lin & 7;
    int i   = lin >> 3;                      // 0..255
    int rid = xcd + 8 * (i >> 4);            // 0..127 (rect, XCD-pinned)
    int idx = i & 15;                        // position within rect
    int mi4 = idx & 1, ni4 = idx >> 1;       // 2 M-tiles x 8 N-tiles
    int b   = rid >> 5;
    int rem = rid & 31;
    int rm  = rem & 7, rn = rem >> 3;        // 8 rect-rows x 4 rect-cols
    int j0  = (rm * 2 + mi4) * 256;
    int ky  = rn * 8 + ni4;                  // 0..31
    int kc0 = ky * 128;
    const unsigned short* A  = Qt + ((size_t)b * N_ + j0) * C_;
    const unsigned short* Bm = Kt + ((size_t)b * N_ + kc0) * C_;

    int t = threadIdx.x;
    int w = t >> 6, lane = t & 63, l15 = lane & 15, quad = lane >> 4;
    int wm = w >> 1, wn = w & 1;
    int srow = lane >> 2;                              // row within 16-row seg
    int sch  = ((lane & 3) ^ ((lane >> 3) & 3)) * 8;   // swizzled source chunk
    int slotq = (quad ^ ((l15 >> 1) & 3)) * 8;         // frag-read slot

    // per-thread global staging pointers (advance 32 elems/tile)
    const unsigned short* gA0 = A + ((size_t)(w * 2 + 0) * 16 + srow) * C_ + sch;
    const unsigned short* gA1 = A + ((size_t)(w * 2 + 1) * 16 + srow) * C_ + sch;
    const unsigned short* gB  = Bm + ((size_t)w * 16 + srow) * C_ + sch;

    f32x4 acc[4][4] = {};
    const int NT = 16;                       // K=512 / BK=32
    unsigned short* bA = sm;                 // read buf (tile tt)
    unsigned short* bB = sm + 12288;         // next (tile tt+1)
    unsigned short* bC = sm + 24576;         // stage target (tile tt+2)

    // prologue: tiles 0 -> bA, 1 -> bB (6 loads/thread)
    async16(gA0,      bA + (w * 2 + 0) * 512);
    async16(gA1,      bA + (w * 2 + 1) * 512);
    async16(gB,       bA + 8192 + w * 512);
    async16(gA0 + 32, bB + (w * 2 + 0) * 512);
    async16(gA1 + 32, bB + (w * 2 + 1) * 512);
    async16(gB  + 32, bB + 8192 + w * 512);
    gA0 += 64; gA1 += 64; gB += 64;
    __builtin_amdgcn_s_waitcnt(0x3F73);      // vmcnt(3): tile 0 landed
    __builtin_amdgcn_s_barrier();

    for (int tt = 0; tt < NT; ++tt) {
        if (tt + 2 < NT) {                   // stage tile tt+2 into bC
            async16(gA0, bC + (w * 2 + 0) * 512);
            async16(gA1, bC + (w * 2 + 1) * 512);
            async16(gB,  bC + 8192 + w * 512);
            gA0 += 32; gA1 += 32; gB += 32;
        }
        bf16x8 af[4], bfr[4];
#pragma unroll
        for (int mi = 0; mi < 4; ++mi)
            af[mi] = *(const bf16x8*)&bA[(wm * 64 + mi * 16 + l15) * 32 + slotq];
#pragma unroll
        for (int ni = 0; ni < 4; ++ni)
            bfr[ni] = *(const bf16x8*)&bA[8192 + (wn * 64 + ni * 16 + l15) * 32 + slotq];
        __builtin_amdgcn_s_setprio(1);
#pragma unroll
        for (int mi = 0; mi < 4; ++mi)
#pragma unroll
            for (int ni = 0; ni < 4; ++ni)
                acc[mi][ni] = MFMA16(af[mi], bfr[ni], acc[mi][ni]);
        __builtin_amdgcn_s_setprio(0);
        if (tt + 1 < NT) {
            if (tt + 2 < NT) __builtin_amdgcn_s_waitcnt(0x3F73); // vmcnt(3)
            else             __builtin_amdgcn_s_waitcnt(0x3F70); // vmcnt(0)
            __builtin_amdgcn_s_barrier();
        }
        unsigned short* tmp = bA; bA = bB; bB = bC; bC = tmp;    // rotate ring
    }

    // ---- epilogue: exp + P store + per-wave rowsum partials
#pragma unroll
    for (int mi = 0; mi < 4; ++mi) {
        float rs[4] = {0.f, 0.f, 0.f, 0.f};
#pragma unroll
        for (int ni = 0; ni < 4; ++ni) {
            int ncol = kc0 + wn * 64 + ni * 16 + l15;
#pragma unroll
            for (int r = 0; r < 4; ++r) {
                int mrow = j0 + wm * 64 + mi * 16 + quad * 4 + r;
                float p = exp2f(__builtin_fmaf(acc[mi][ni][r], SC2, -ES2));
                rs[r] += p;
                P[((size_t)b * N_ + mrow) * N_ + ncol] = f2bf(p);
            }
        }
#pragma unroll
        for (int r = 0; r < 4; ++r) {
            float v = rs[r];
            v += __shfl_xor(v, 1);
            v += __shfl_xor(v, 2);
            v += __shfl_xor(v, 4);
            v += __shfl_xor(v, 8);
            if (l15 == 0)
                psum[(size_t)(ky * 2 + wn) * 16384 +
                     (size_t)b * N_ + j0 + wm * 64 + mi * 16 + quad * 4 + r] = v;
        }
    }
}

// ------------- GEMM2 (R11): O = (P V) / l -> AObf[b][n][c] bf16 -------------
// 256x128 tile, 8 waves (4M x 2N), BK=32, ring-4 LDS, stage-depth-2,
// barrier every 2 tiles; mid-window wave-local vmcnt(3)+sched_barrier.
// XCD swizzle: the 4 ct-blocks sharing a 2 MB P-tile land on one XCD.
__global__ __launch_bounds__(512, 2) void gemm_pv(const unsigned short* __restrict__ P,
                                                  const unsigned short* __restrict__ Vg,
                                                  const float* __restrict__ psum,
                                                  unsigned short* __restrict__ ao) {
    extern __shared__ unsigned short sm[];   // 4 bufs x (A 8192 | B 4096) ushorts
    __shared__ float linv[256];
    int lin = blockIdx.x;                    // 0..255
    int xcd = lin & 7;
    int i4  = lin >> 3;                      // 0..31
    int ct  = i4 & 3;
    int grp = xcd + 8 * (i4 >> 2);           // 0..63
    int b = grp & 3, qtile = grp >> 2;
    int j0 = qtile * 256, co0 = ct * 128;
    int t = threadIdx.x;
    int w = t >> 6, lane = t & 63, l15 = lane & 15, quad = lane >> 4;
    int wm = w >> 1, wn = w & 1;
    int srow = lane >> 2;
    int sch  = ((lane & 3) ^ ((lane >> 3) & 3)) * 8;
    int slotq = (quad ^ ((l15 >> 1) & 3)) * 8;
    const unsigned short* A  = P  + ((size_t)b * N_ + j0) * N_;
    const unsigned short* Bm = Vg + ((size_t)b * C_ + co0) * N_;
    f32x4 acc[4][4] = {};
    const int NT = 128;                      // K = 4096 / 32
    // prologue: stage tiles 0,1 (6 loads/thread)
#pragma unroll
    for (int tt = 0; tt < 2; ++tt) {
        unsigned short* dst = sm + tt * 12288;
        size_t k0 = (size_t)tt << 5;
#pragma unroll
        for (int i = 0; i < 2; ++i) {
            int seg = w * 2 + i;
            size_t row = (size_t)seg * 16 + srow;
            async16(&A[row * N_ + k0 + sch], dst + seg * 512);
        }
        {
            size_t row = (size_t)w * 16 + srow;
            async16(&Bm[row * N_ + k0 + sch], dst + 8192 + w * 512);
        }
    }
    // linv (psum reduction) overlaps the prologue loads
    if (t < 256) {
        size_t q = (size_t)b * N_ + j0 + t;
        float s = 0.f;
#pragma unroll
        for (int i = 0; i < 64; ++i) s += psum[(size_t)i * 16384 + q];
        linv[t] = 1.f / s;
    }
    __builtin_amdgcn_s_waitcnt(0x3F73);      // vmcnt(3): tile 0 landed, 1 in flight
    __builtin_amdgcn_s_barrier();
    for (int tt = 0; tt < NT; tt += 2) {
#pragma unroll
        for (int s = 0; s < 2; ++s) {
            int tc = tt + s;
            const unsigned short* bp = sm + (tc & 3) * 12288;
            int ts = tc + 2;                 // stage target (depth-2)
            bf16x8 af[4], bfr[4];
#pragma unroll
            for (int mi = 0; mi < 4; ++mi)
                af[mi] = *(const bf16x8*)&bp[(wm * 64 + mi * 16 + l15) * 32 + slotq];
#pragma unroll
            for (int ni = 0; ni < 4; ++ni)
                bfr[ni] = *(const bf16x8*)&bp[8192 + (wn * 64 + ni * 16 + l15) * 32 + slotq];
            if (ts < NT) {
                unsigned short* stg = sm + (ts & 3) * 12288;
                size_t k0n = (size_t)ts << 5;
#pragma unroll
                for (int i = 0; i < 2; ++i) {
                    int seg = w * 2 + i;
                    size_t row = (size_t)seg * 16 + srow;
                    async16(&A[row * N_ + k0n + sch], stg + seg * 512);
                }
                {
                    size_t row = (size_t)w * 16 + srow;
                    async16(&Bm[row * N_ + k0n + sch], stg + 8192 + w * 512);
                }
            }
            __builtin_amdgcn_s_setprio(1);
#pragma unroll
            for (int mi = 0; mi < 4; ++mi)
#pragma unroll
                for (int ni = 0; ni < 4; ++ni)
                    acc[mi][ni] = MFMA16(af[mi], bfr[ni], acc[mi][ni]);
            __builtin_amdgcn_s_setprio(0);
            if (s == 0) {                    // mid-window: wave-local counted wait
                if (tt + 2 < NT) __builtin_amdgcn_s_waitcnt(0x3F73); // vmcnt(3)
                else             __builtin_amdgcn_s_waitcnt(0x3F70); // vmcnt(0)
                __builtin_amdgcn_sched_barrier(0);
            }
        }
        if (tt + 2 < NT) {                   // window boundary
            if (tt + 3 < NT) __builtin_amdgcn_s_waitcnt(0x3F73);     // vmcnt(3)
            else             __builtin_amdgcn_s_waitcnt(0x3F70);     // vmcnt(0)
            __builtin_amdgcn_s_barrier();
        }
    }
    // epilogue: scale by 1/l and store
#pragma unroll
    for (int mi = 0; mi < 4; ++mi)
#pragma unroll
        for (int ni = 0; ni < 4; ++ni)
#pragma unroll
            for (int r = 0; r < 4; ++r) {
                int mrow = wm * 64 + mi * 16 + quad * 4 + r;
                int ncol = wn * 64 + ni * 16 + l15;
                ao[((size_t)b * N_ + j0 + mrow) * C_ + co0 + ncol] =
                    f2bf(acc[mi][ni][r] * linv[mrow]);
            }
}

// ------------- final projection + residual: grid (32, 4, 4) -----------------
__global__ __launch_bounds__(256) void gemm_resid(const unsigned short* __restrict__ AObf,
                                                  const unsigned short* __restrict__ Wo,
                                                  const float* __restrict__ bo,
                                                  const float* __restrict__ xres,
                                                  float* __restrict__ out) {
    int b = blockIdx.z, j0 = blockIdx.x * 128, co0 = blockIdx.y * 128;
    const unsigned short* A = AObf + ((size_t)b * N_ + j0) * C_;
    const unsigned short* B = Wo + (size_t)co0 * C_;
    gemm_core(A, B, C_, C_, C_,
        [&](f32x4 (&acc)[4][4], int wm, int wn, int l15, int quad) {
#pragma unroll
        for (int mi = 0; mi < 4; ++mi)
#pragma unroll
            for (int ni = 0; ni < 4; ++ni) {
                int ncol = wn * 64 + ni * 16 + l15;
                int jb = j0 + wm * 64 + mi * 16 + quad * 4;
                size_t o = ((size_t)b * C_ + co0 + ncol) * N_ + jb;
                float bb = bo[co0 + ncol];
                float4 xr = *(const float4*)&xres[o];
                float4 ov;
                ov.x = acc[mi][ni][0] + bb + xr.x;
                ov.y = acc[mi][ni][1] + bb + xr.y;
                ov.z = acc[mi][ni][2] + bb + xr.z;
                ov.w = acc[mi][ni][3] + bb + xr.w;
                *(float4*)&out[o] = ov;
            }
    });
}

// ------------- FALLBACK: R4 flash attention (if ws too small) ---------------
__global__ __launch_bounds__(256, 1) void flash_attn(const unsigned short* __restrict__ Qt,
                                                     const unsigned short* __restrict__ Kt,
                                                     const unsigned short* __restrict__ Vg,
                                                     unsigned short* __restrict__ part,
                                                     float* __restrict__ lbuf,
                                                     int nsplit) {
    extern __shared__ unsigned short smem[];
    unsigned short* Kl = smem;
    unsigned short* Vl = smem + 32768;
    unsigned short* Pl = smem + 65536;

    int flat = blockIdx.x;
    int qblk, b, s;
    if (nsplit == 2) { s = flat & 1; b = (flat >> 1) & 3; qblk = flat >> 3; }
    else             { s = 0;        b = flat & 3;        qblk = flat >> 2; }
    int q0 = qblk * 128;
    int t = threadIdx.x, w = t >> 6, lane = t & 63, l15 = lane & 15, quad = lane >> 4;
    int klen = N_ / nsplit, kbeg = s * klen, nkt = klen / 32;
    int xr = l15 & 7;

    const unsigned short* Kbase = Kt + (size_t)b * N_ * C_;
    const unsigned short* Vbase = Vg + (size_t)b * C_ * N_;

    bf16x8 qa[2][16];
#pragma unroll
    for (int u = 0; u < 2; ++u) {
        const unsigned short* qb =
            Qt + ((size_t)b * N_ + q0 + w * 32 + u * 16 + l15) * C_ + quad * 8;
#pragma unroll
        for (int ck = 0; ck < 16; ++ck) qa[u][ck] = *(const bf16x8*)(qb + ck * 32);
    }

    f32x4 o[2][32] = {};
    float lrow[2][4] = {};

    {
        int k0 = kbeg;
#pragma unroll
        for (int i = 0; i < 8; ++i) {
            int r = w * 8 + i;
            async16(Kbase + (size_t)(k0 + r) * C_ + ((lane ^ (r & 7)) * 8), Kl + r * 512);
        }
#pragma unroll
        for (int i = 0; i < 8; ++i) {
            int idx = w * 8 + i, kc = idx >> 3, cb = idx & 7;
            async16(Vbase + (size_t)(cb * 64 + lane) * N_ + k0 + kc * 8,
                    Vl + (kc * 512 + cb * 64) * 8);
        }
    }

    for (int kt = 0; kt < nkt; ++kt) {
        int cur = kt & 1, nxt = cur ^ 1;
        __builtin_amdgcn_s_waitcnt(0x3F70);
        __syncthreads();
        if (kt + 1 < nkt) {
            int k0 = kbeg + (kt + 1) * 32;
#pragma unroll
            for (int i = 0; i < 8; ++i) {
                int r = w * 8 + i;
                async16(Kbase + (size_t)(k0 + r) * C_ + ((lane ^ (r & 7)) * 8),
                        Kl + nxt * 16384 + r * 512);
            }
#pragma unroll
            for (int i = 0; i < 8; ++i) {
                int idx = w * 8 + i, kc = idx >> 3, cb = idx & 7;
                async16(Vbase + (size_t)(cb * 64 + lane) * N_ + k0 + kc * 8,
                        Vl + nxt * 16384 + (kc * 512 + cb * 64) * 8);
            }
        }
        const unsigned short* Kc = Kl + cur * 16384;
        f32x4 s00 = {}, s01 = {}, s10 = {}, s11 = {};
#pragma unroll
        for (int ck = 0; ck < 16; ++ck) {
            int slot = (ck * 4 + quad) ^ xr;
            bf16x8 b0 = *(const bf16x8*)&Kc[l15 * 512 + slot * 8];
            bf16x8 b1 = *(const bf16x8*)&Kc[(16 + l15) * 512 + slot * 8];
            s00 = MFMA16(qa[0][ck], b0, s00);
            s10 = MFMA16(qa[1][ck], b0, s10);
            s01 = MFMA16(qa[0][ck], b1, s01);
            s11 = MFMA16(qa[1][ck], b1, s11);
        }
        unsigned short* pb = &Pl[w * 1152];
#pragma unroll
        for (int r = 0; r < 4; ++r) {
            float p00 = __expf(s00[r] * SCALE - ESHIFT);
            float p01 = __expf(s01[r] * SCALE - ESHIFT);
            float p10 = __expf(s10[r] * SCALE - ESHIFT);
            float p11 = __expf(s11[r] * SCALE - ESHIFT);
            lrow[0][r] += p00 + p01;
            lrow[1][r] += p10 + p11;
            int row0 = (quad * 4 + r) * 36;
            int row1 = (16 + quad * 4 + r) * 36;
            pb[row0 + l15]      = f2bf(p00);
            pb[row0 + 16 + l15] = f2bf(p01);
            pb[row1 + l15]      = f2bf(p10);
            pb[row1 + 16 + l15] = f2bf(p11);
        }
        __builtin_amdgcn_s_waitcnt(0xC07F);
        bf16x8 pa0 = *(const bf16x8*)&Pl[w * 1152 + l15 * 36 + quad * 8];
        bf16x8 pa1 = *(const bf16x8*)&Pl[w * 1152 + (16 + l15) * 36 + quad * 8];
        const unsigned short* Vc = Vl + cur * 16384;
#pragma unroll
        for (int cf = 0; cf < 32; ++cf) {
            bf16x8 vb = *(const bf16x8*)&Vc[(quad * 512 + cf * 16 + l15) * 8];
            o[0][cf] = MFMA16(pa0, vb, o[0][cf]);
            o[1][cf] = MFMA16(pa1, vb, o[1][cf]);
        }
    }
#pragma unroll
    for (int u = 0; u < 2; ++u)
#pragma unroll
        for (int r = 0; r < 4; ++r) {
            float l = lrow[u][r];
            l += __shfl_xor(l, 1);
            l += __shfl_xor(l, 2);
            l += __shfl_xor(l, 4);
            l += __shfl_xor(l, 8);
            lrow[u][r] = l;
        }
    size_t pbase = (size_t)(s * B_ + b) * N_;
#pragma unroll
    for (int u = 0; u < 2; ++u)
#pragma unroll
        for (int cf = 0; cf < 32; ++cf)
#pragma unroll
            for (int r = 0; r < 4; ++r) {
                int q = q0 + w * 32 + u * 16 + quad * 4 + r;
                part[(pbase + q) * C_ + cf * 16 + l15] = f2bf(o[u][cf][r]);
            }
    if (l15 == 0) {
#pragma unroll
        for (int u = 0; u < 2; ++u)
#pragma unroll
            for (int r = 0; r < 4; ++r) {
                int q = q0 + w * 32 + u * 16 + quad * 4 + r;
                lbuf[pbase + q] = lrow[u][r];
            }
    }
}

__global__ __launch_bounds__(256) void attn_combine(const unsigned short* __restrict__ part,
                                                    const float* __restrict__ lbuf,
                                                    unsigned short* __restrict__ ao,
                                                    int nsplit) {
    size_t idx = (size_t)blockIdx.x * 256 + threadIdx.x;
    int cu = (int)(idx & 63);
    size_t row = idx >> 6;
    float l = lbuf[row];
    union { uint4 v; unsigned short u[8]; } p1, p2, outv;
    p1.v = *(const uint4*)&part[row * C_ + cu * 8];
    if (nsplit == 2) {
        l += lbuf[(size_t)B_ * N_ + row];
        p2.v = *(const uint4*)&part[((size_t)B_ * N_ + row) * C_ + cu * 8];
    } else {
        p2.v = make_uint4(0, 0, 0, 0);
    }
    float inv = 1.f / l;
#pragma unroll
    for (int j = 0; j < 8; ++j)
        outv.u[j] = f2bf((bf2f(p1.u[j]) + bf2f(p2.u[j])) * inv);
    *(uint4*)&ao[row * C_ + cu * 8] = outv.v;
}

// ---------------------------------------------------------------------------
extern "C" void kernel_launch(void* const* d_in, const int* in_sizes, int n_in,
                              void* d_out, int out_size, void* d_ws, size_t ws_size,
                              hipStream_t stream) {
    const float* x   = (const float*)d_in[0];
    const float* gam = (const float*)d_in[1];
    const float* bet = (const float*)d_in[2];
    const float* wq  = (const float*)d_in[3];
    const float* bq  = (const float*)d_in[4];
    const float* wk  = (const float*)d_in[5];
    const float* bk  = (const float*)d_in[6];
    const float* wv  = (const float*)d_in[7];
    const float* bv  = (const float*)d_in[8];
    const float* wo  = (const float*)d_in[9];
    const float* bo  = (const float*)d_in[10];
    float* out = (float*)d_out;

    char* ws = (char*)d_ws;
    const size_t SZH = (size_t)B_ * N_ * C_ * 2;          // 16 MiB bf16 tensor
    const size_t OFF_HT = 4096;
    const size_t OFF_QT = OFF_HT + SZH;
    const size_t OFF_KT = OFF_QT + SZH;
    const size_t OFF_VG = OFF_KT + SZH;
    const size_t OFF_WB = OFF_VG + SZH;
    const size_t OFF_X  = OFF_WB + 2097152;               // 69,210,112
    float*          part0 = (float*)ws;                   // gn partial sums
    unsigned short* Ht    = (unsigned short*)(ws + OFF_HT);
    unsigned short* Qt    = (unsigned short*)(ws + OFF_QT);
    unsigned short* Kt    = (unsigned short*)(ws + OFF_KT);
    unsigned short* Vg    = (unsigned short*)(ws + OFF_VG);
    unsigned short* Wb    = (unsigned short*)(ws + OFF_WB);
    unsigned short* AObf  = Ht;  // Ht dead after projections

    // Path A: materialized-P two-GEMM attention.
    const size_t SZPSUM = 64ull * 16384 * 4;              // 4 MiB
    const size_t SZP    = (size_t)B_ * N_ * N_ * 2;       // 128 MiB
    float*          psum = (float*)(ws + OFF_X);
    unsigned short* P    = (unsigned short*)(ws + OFF_X + SZPSUM);
    size_t needA = OFF_X + SZPSUM + SZP;

    // Path B (fallback): R4 flash.
    float*          lbuf = (float*)(ws + OFF_X);
    unsigned short* partb = (unsigned short*)(ws + OFF_X + 262144);
    size_t needB2 = OFF_X + 262144 + 2 * SZH;

    gn_partial<<<512, 256, 0, stream>>>(x, part0);
    gn_apply<<<dim3(64, 8, B_), 256, 0, stream>>>(x, gam, bet, part0, Ht);
    wconv<<<4096, 256, 0, stream>>>(wq, wk, wv, wo, Wb);
    gemm_qkv<<<dim3(32, 12, B_), 256, 0, stream>>>(Ht, Wb, bq, bk, bv, Qt, Kt, Vg);

    if (ws_size >= needA) {
        const int QK_LDS = 73728;    // 3 ring bufs x 24 KiB
        (void)hipFuncSetAttribute((const void*)gemm_qk_exp,
                                  hipFuncAttributeMaxDynamicSharedMemorySize, QK_LDS);
        gemm_qk_exp<<<2048, 512, QK_LDS, stream>>>(Qt, Kt, P, psum);
        const int PV_LDS = 98304;    // 4 ring bufs x 24 KiB
        (void)hipFuncSetAttribute((const void*)gemm_pv,
                                  hipFuncAttributeMaxDynamicSharedMemorySize, PV_LDS);
        gemm_pv<<<256, 512, PV_LDS, stream>>>(P, Vg, psum, AObf);
    } else {
        int nsplit = (ws_size >= needB2) ? 2 : 1;
        const int FLASH_LDS = 140288;
        (void)hipFuncSetAttribute((const void*)flash_attn,
                                  hipFuncAttributeMaxDynamicSharedMemorySize, FLASH_LDS);
        flash_attn<<<dim3(32 * B_ * nsplit), 256, FLASH_LDS, stream>>>(Qt, Kt, Vg, partb, lbuf, nsplit);
        attn_combine<<<4096, 256, 0, stream>>>(partb, lbuf, AObf, nsplit);
    }
    gemm_resid<<<dim3(32, 4, B_), 256, 0, stream>>>(AObf, Wb + 786432, bo, x, out);
}